// Round 3
// baseline (178.499 us; speedup 1.0000x reference)
//
#include <hip/hip_runtime.h>

#define SEQ 2048
#define D_MODEL 1024
#define NTOK 4096
#define PROW 4096
#define DH 64
#define LN_EPS 1e-5f
#define SHEP_EPS 1e-4f

typedef __attribute__((ext_vector_type(8))) short bf16x8;
typedef __attribute__((ext_vector_type(4))) short s16x4;
typedef __attribute__((ext_vector_type(4))) float f32x4;

__device__ __forceinline__ unsigned short f2bf(float f) {
  union { float f; unsigned u; } v; v.f = f;
  unsigned r = v.u + 0x7fffu + ((v.u >> 16) & 1u);
  return (unsigned short)(r >> 16);
}
__device__ __forceinline__ float bf2f(unsigned short s) {
  union { unsigned u; float f; } v; v.u = ((unsigned)s) << 16;
  return v.f;
}
__device__ __forceinline__ void gload16(const void* g, void* l) {
  __builtin_amdgcn_global_load_lds(
      (const __attribute__((address_space(1))) unsigned int*)g,
      (__attribute__((address_space(3))) unsigned int*)l, 16, 0, 0);
}
__device__ __forceinline__ void gload4(const void* g, void* l) {
  __builtin_amdgcn_global_load_lds(
      (const __attribute__((address_space(1))) unsigned int*)g,
      (__attribute__((address_space(3))) unsigned int*)l, 4, 0, 0);
}
__device__ __forceinline__ unsigned cvt_pk_bf16(float lo, float hi) {
  unsigned r;
  asm("v_cvt_pk_bf16_f32 %0, %1, %2" : "=v"(r) : "v"(lo), "v"(hi));
  return r;
}
#define MFMA16(a, b, c) __builtin_amdgcn_mfma_f32_16x16x32_bf16(a, b, c, 0, 0, 0)

// ---------------- LayerNorm: f32 row -> bf16 row ----------------
__global__ __launch_bounds__(256) void ln_kernel(const float* __restrict__ X,
                                                 unsigned short* __restrict__ Xn) {
  int row = blockIdx.x, tid = threadIdx.x;
  const float4* xr = (const float4*)(X + (size_t)row * D_MODEL);
  float4 v = xr[tid];
  float s = v.x + v.y + v.z + v.w;
  float s2 = v.x * v.x + v.y * v.y + v.z * v.z + v.w * v.w;
#pragma unroll
  for (int off = 32; off > 0; off >>= 1) {
    s += __shfl_down(s, off);
    s2 += __shfl_down(s2, off);
  }
  __shared__ float red[8];
  __shared__ float mb[2];
  int wv = tid >> 6;
  if ((tid & 63) == 0) { red[wv] = s; red[4 + wv] = s2; }
  __syncthreads();
  if (tid == 0) {
    float ts = red[0] + red[1] + red[2] + red[3];
    float t2 = red[4] + red[5] + red[6] + red[7];
    float mu = ts * (1.f / D_MODEL);
    float var = t2 * (1.f / D_MODEL) - mu * mu;
    mb[0] = mu;
    mb[1] = rsqrtf(var + LN_EPS);
  }
  __syncthreads();
  float mu = mb[0], rs = mb[1];
  s16x4 o;
  o[0] = (short)f2bf((v.x - mu) * rs);
  o[1] = (short)f2bf((v.y - mu) * rs);
  o[2] = (short)f2bf((v.z - mu) * rs);
  o[3] = (short)f2bf((v.w - mu) * rs);
  ((s16x4*)(Xn + (size_t)row * D_MODEL))[tid] = o;
}

// ---------------- f32 -> bf16 convert (weights) ----------------
__global__ __launch_bounds__(256) void cvt_bf16_kernel(const float* __restrict__ in,
                                                       unsigned short* __restrict__ out,
                                                       int n4) {
  int i = blockIdx.x * 256 + threadIdx.x;
  if (i >= n4) return;
  float4 v = ((const float4*)in)[i];
  s16x4 o;
  o[0] = (short)f2bf(v.x);
  o[1] = (short)f2bf(v.y);
  o[2] = (short)f2bf(v.z);
  o[3] = (short)f2bf(v.w);
  ((s16x4*)out)[i] = o;
}

// ---------------- GEMM (NT, bf16 in, bf16 out + bias) : P = Xn*Wi^T + b ----------------
__global__ __launch_bounds__(256) void gemm_p_kernel(
    const unsigned short* __restrict__ A, const unsigned short* __restrict__ B,
    const float* __restrict__ bias, unsigned short* __restrict__ C,
    int M, int N, int K) {
  __shared__ __align__(16) unsigned short sA[128 * 32];
  __shared__ __align__(16) unsigned short sB[128 * 32];
  int tid = threadIdx.x;
  int m0 = blockIdx.y * 128, n0 = blockIdx.x * 128;
  int wv = tid >> 6, lane = tid & 63;
  int wr = wv >> 1, wc = wv & 1;
  int lr = lane & 15, lq = lane >> 4;
  f32x4 acc[4][4] = {};
  int srow = tid >> 2, scol = (tid & 3) * 8;
  const unsigned short* gA = A + (size_t)(m0 + srow) * K + scol;
  const unsigned short* gB = B + (size_t)(n0 + srow) * K + scol;
  unsigned short* lA = sA + tid * 8;
  unsigned short* lB = sB + tid * 8;
  for (int k0 = 0; k0 < K; k0 += 32) {
    gload16(gA + k0, lA);
    gload16(gA + k0 + (size_t)64 * K, lA + 64 * 32);
    gload16(gB + k0, lB);
    gload16(gB + k0 + (size_t)64 * K, lB + 64 * 32);
    __syncthreads();
    bf16x8 af[4], bfr[4];
#pragma unroll
    for (int m = 0; m < 4; m++)
      af[m] = *(const bf16x8*)&sA[(wr * 64 + m * 16 + lr) * 32 + lq * 8];
#pragma unroll
    for (int n = 0; n < 4; n++)
      bfr[n] = *(const bf16x8*)&sB[(wc * 64 + n * 16 + lr) * 32 + lq * 8];
#pragma unroll
    for (int m = 0; m < 4; m++)
#pragma unroll
      for (int n = 0; n < 4; n++)
        acc[m][n] = MFMA16(af[m], bfr[n], acc[m][n]);
    __syncthreads();
  }
#pragma unroll
  for (int m = 0; m < 4; m++) {
    int row = m0 + wr * 64 + m * 16 + lq * 4;
#pragma unroll
    for (int n = 0; n < 4; n++) {
      int col = n0 + wc * 64 + n * 16 + lr;
      float bv = bias[col];
#pragma unroll
      for (int r = 0; r < 4; r++)
        C[(size_t)(row + r) * N + col] = f2bf(acc[m][n][r] + bv);
    }
  }
}

// ---------------- GEMM (NT) + residual + bias, f32 out : out = X + O*Wo^T + b ----------------
__global__ __launch_bounds__(256) void gemm_out_kernel(
    const unsigned short* __restrict__ A, const unsigned short* __restrict__ B,
    const float* __restrict__ bias, const float* __restrict__ Xres,
    float* __restrict__ Out, int M, int N, int K) {
  __shared__ __align__(16) unsigned short sA[128 * 32];
  __shared__ __align__(16) unsigned short sB[128 * 32];
  int tid = threadIdx.x;
  int m0 = blockIdx.y * 128, n0 = blockIdx.x * 128;
  int wv = tid >> 6, lane = tid & 63;
  int wr = wv >> 1, wc = wv & 1;
  int lr = lane & 15, lq = lane >> 4;
  f32x4 acc[4][4] = {};
  int srow = tid >> 2, scol = (tid & 3) * 8;
  const unsigned short* gA = A + (size_t)(m0 + srow) * K + scol;
  const unsigned short* gB = B + (size_t)(n0 + srow) * K + scol;
  unsigned short* lA = sA + tid * 8;
  unsigned short* lB = sB + tid * 8;
  for (int k0 = 0; k0 < K; k0 += 32) {
    gload16(gA + k0, lA);
    gload16(gA + k0 + (size_t)64 * K, lA + 64 * 32);
    gload16(gB + k0, lB);
    gload16(gB + k0 + (size_t)64 * K, lB + 64 * 32);
    __syncthreads();
    bf16x8 af[4], bfr[4];
#pragma unroll
    for (int m = 0; m < 4; m++)
      af[m] = *(const bf16x8*)&sA[(wr * 64 + m * 16 + lr) * 32 + lq * 8];
#pragma unroll
    for (int n = 0; n < 4; n++)
      bfr[n] = *(const bf16x8*)&sB[(wc * 64 + n * 16 + lr) * 32 + lq * 8];
#pragma unroll
    for (int m = 0; m < 4; m++)
#pragma unroll
      for (int n = 0; n < 4; n++)
        acc[m][n] = MFMA16(af[m], bfr[n], acc[m][n]);
    __syncthreads();
  }
#pragma unroll
  for (int m = 0; m < 4; m++) {
    int row = m0 + wr * 64 + m * 16 + lq * 4;
#pragma unroll
    for (int n = 0; n < 4; n++) {
      int col = n0 + wc * 64 + n * 16 + lr;
      float bv = bias[col];
#pragma unroll
      for (int r = 0; r < 4; r++) {
        size_t idx = (size_t)(row + r) * N + col;
        Out[idx] = Xres[idx] + acc[m][n][r] + bv;
      }
    }
  }
}

// ---------------- V transpose: P's V slice [t][c] -> Vt[bh][c][t] ----------------
__global__ __launch_bounds__(256) void transv_kernel(const unsigned short* __restrict__ P,
                                                     unsigned short* __restrict__ Vt) {
  int kt = blockIdx.x;  // t-tile of 64
  int bh = blockIdx.y;
  int b = bh >> 4, h = bh & 15;
  __shared__ unsigned short sT[64][72];  // [c][k]
  int tid = threadIdx.x;
  const unsigned short* vbase = P + ((size_t)(b * SEQ + kt * 64)) * PROW + h * 256 + 128;
#pragma unroll
  for (int it = 0; it < 2; it++) {
    int c = tid + it * 256;
    int k = c >> 3, c0 = (c & 7) * 8;
    uint4 u = *(const uint4*)(vbase + (size_t)k * PROW + c0);
    unsigned e[4] = {u.x, u.y, u.z, u.w};
#pragma unroll
    for (int j = 0; j < 4; j++) {
      sT[c0 + 2 * j][k] = (unsigned short)(e[j] & 0xffffu);
      sT[c0 + 2 * j + 1][k] = (unsigned short)(e[j] >> 16);
    }
  }
  __syncthreads();
  unsigned short* obase = Vt + (size_t)bh * 64 * SEQ + kt * 64;
#pragma unroll
  for (int it = 0; it < 2; it++) {
    int cc = tid + it * 256;
    int crow = cc >> 3, k0 = (cc & 7) * 8;
    uint4 o;
    unsigned short e[8];
#pragma unroll
    for (int j = 0; j < 8; j++) e[j] = sT[crow][k0 + j];
    o.x = (unsigned)e[0] | ((unsigned)e[1] << 16);
    o.y = (unsigned)e[2] | ((unsigned)e[3] << 16);
    o.z = (unsigned)e[4] | ((unsigned)e[5] << 16);
    o.w = (unsigned)e[6] | ((unsigned)e[7] << 16);
    *(uint4*)(obase + (size_t)crow * SEQ + k0) = o;
  }
}

// ---------------- row norms of Q and K slices (from bf16 P) ----------------
__global__ __launch_bounds__(256) void norms_kernel(const unsigned short* __restrict__ P,
                                                    float* __restrict__ nrm) {
  int id = blockIdx.x * 256 + threadIdx.x;  // 32*2*2048
  int bh = id >> 12;
  int which = (id >> 11) & 1;
  int t = id & 2047;
  int b = bh >> 4, h = bh & 15;
  const unsigned short* p = P + ((size_t)(b * SEQ + t)) * PROW + h * 256 + which * 64;
  const uint4* pv = (const uint4*)p;
  float acc = 0.f;
#pragma unroll
  for (int i = 0; i < 8; i++) {
    uint4 u = pv[i];
    unsigned arr[4] = {u.x, u.y, u.z, u.w};
#pragma unroll
    for (int j = 0; j < 4; j++) {
      float lo = __uint_as_float(arr[j] << 16);
      float hi = __uint_as_float(arr[j] & 0xffff0000u);
      acc += lo * lo + hi * hi;
    }
  }
  nrm[(size_t)(bh * 2 + which) * SEQ + t] = acc;
}

// ---------------- Shepard attention (16 waves, 128 q-rows/block) ----------------
// Wave-groups: waves 0-7 process even key-tiles, 8-15 odd key-tiles of the
// SAME 128 q-rows (each wave owns 16 q-rows); partial num/den combined via
// LDS at the end. 1024 thr/block -> 2 blocks/CU = 32 waves/CU cap.
// sQW: Q staged in rows 0-127, dead after qf hoist; wave w's W slab is rows
// 16w..16w+15 (wave-private; the loop's first barrier orders hoist reads
// before iter-0 W writes via its lgkmcnt(0) drain).
// K/V: even/odd tile pair staged per iter, m97 2-barrier style.
// All 2-D LDS tiles: 128-B rows, 16-B-group XOR swizzle grp^=(row&7), applied
// on the pre-swizzled global source (gload_lds writes linearly) + all ds ops.
__global__ __launch_bounds__(1024, 8) void attn_kernel(
    const unsigned short* __restrict__ P, const unsigned short* __restrict__ Vt,
    const float* __restrict__ nrm, unsigned short* __restrict__ O) {
  int qt = blockIdx.x, bh = blockIdx.y;
  int b = bh >> 4, h = bh & 15;
  int tid = threadIdx.x;
  int w = tid >> 6, lane = tid & 63;
  int lr = lane & 15, lq = lane >> 4;
  int wg = w >> 3;  // key-group: 0=even tiles, 1=odd tiles
  int wq = w & 7;   // q-row wave: rows 16*wq..16*wq+15

  __shared__ __align__(16) unsigned short sQW[256 * 64];     // Q (rows 0-127) / W slabs (rows 16w)
  __shared__ __align__(16) unsigned short sKV[2][2][64 * 64]; // [K=0,V=1][tile parity][..]
  __shared__ __align__(16) float sK2[2][64];
  __shared__ __align__(16) float sDen[16][16];

  const unsigned short* qbase = P + ((size_t)(b * SEQ + qt * 128)) * PROW + h * 256;
  const unsigned short* kbase = P + ((size_t)(b * SEQ)) * PROW + h * 256 + 64;
  const unsigned short* vtb = Vt + (size_t)bh * 64 * SEQ;
  const float* k2base = nrm + (size_t)(bh * 2 + 1) * SEQ;

  // staging geometry: idx = chunk within one 8KB tile, g = which parity I stage
  int sg = wg;               // == tid >> 9
  int idx = tid & 511;
  int srow = idx >> 3;
  int scol = ((idx & 7) ^ (srow & 7)) * 8;
  char* kdst = (char*)&sKV[0][sg][0] + idx * 16;
  char* vdst = (char*)&sKV[1][sg][0] + idx * 16;
  const unsigned short* kSrc = kbase + (size_t)srow * PROW + scol;   // + kt*64*PROW
  const unsigned short* vSrc = vtb + (size_t)srow * SEQ + scol;      // + kt*64

  // ---- prologue: stage Q (1024 x 16B = 16KB), load q2
  {
    int qrow_s = tid >> 3;
    int qcol_s = ((tid & 7) ^ (qrow_s & 7)) * 8;
    gload16(qbase + (size_t)qrow_s * PROW + qcol_s, (char*)sQW + tid * 16);
  }
  float q2 = nrm[(size_t)(bh * 2) * SEQ + qt * 128 + 16 * wq + lr];
  __syncthreads();

  // hoist Q fragments (B-operand of S^T = K.Q^T)
  int qrow = 16 * wq + lr;
  bf16x8 qf[2];
#pragma unroll
  for (int ks = 0; ks < 2; ks++)
    qf[ks] = *(const bf16x8*)((const char*)sQW + qrow * 128 +
                              ((ks * 64 + lq * 16) ^ ((lr & 7) << 4)));

  f32x4 num[4] = {};
  float den = 0.f;
  char* wrow = (char*)sQW + (16 * w + lr) * 128;  // wave-private W slab row

  for (int t = 0; t < SEQ / 128; t++) {
    int kt = 2 * t + wg;
    // stage this iter's K/V tile pair (each thread stages its sg parity)
    gload16(kSrc + (size_t)(2 * t + sg) * 64 * PROW, kdst);
    gload16(vSrc + (size_t)(2 * t + sg) * 64, vdst);
    if (tid < 128) {
      int g2 = tid >> 6;
      gload4(k2base + (2 * t + g2) * 64 + lane, (char*)&sK2[g2][0] + lane * 4);
    }
    __syncthreads();  // drains gloads (vmcnt0) + prior-phase lgkm

    // S^T[k][q] = K . Q^T
    f32x4 st[4] = {};
    __builtin_amdgcn_s_setprio(1);
#pragma unroll
    for (int fk = 0; fk < 4; fk++) {
      int row = 16 * fk + lr;
      const char* krow = (const char*)&sKV[0][wg][0] + row * 128;
      bf16x8 kf0 = *(const bf16x8*)(krow + ((lq * 16) ^ ((row & 7) << 4)));
      bf16x8 kf1 = *(const bf16x8*)(krow + ((64 + lq * 16) ^ ((row & 7) << 4)));
      st[fk] = MFMA16(kf0, qf[0], st[fk]);
      st[fk] = MFMA16(kf1, qf[1], st[fk]);
    }
    __builtin_amdgcn_s_setprio(0);

    // weights: w = rcp(max(q2+k2-2*st, 1e-8)); pack bf16; stash in own W slab
#pragma unroll
    for (int fk = 0; fk < 4; fk++) {
      f32x4 k2v = *(const f32x4*)&sK2[wg][16 * fk + 4 * lq];
      float w0 = __builtin_amdgcn_rcpf(fmaxf(fmaf(-2.f, st[fk][0], q2 + k2v[0]), 1e-8f));
      float w1 = __builtin_amdgcn_rcpf(fmaxf(fmaf(-2.f, st[fk][1], q2 + k2v[1]), 1e-8f));
      float w2 = __builtin_amdgcn_rcpf(fmaxf(fmaf(-2.f, st[fk][2], q2 + k2v[2]), 1e-8f));
      float w3 = __builtin_amdgcn_rcpf(fmaxf(fmaf(-2.f, st[fk][3], q2 + k2v[3]), 1e-8f));
      den += (w0 + w1) + (w2 + w3);
      uint2 pp;
      pp.x = cvt_pk_bf16(w0, w1);
      pp.y = cvt_pk_bf16(w2, w3);
      *(uint2*)(wrow + ((32 * fk + 8 * lq) ^ ((lr & 7) << 4))) = pp;
    }

    // PV: num[c] += W . V^T  (own W slab -> no barrier between write & read)
    __builtin_amdgcn_s_setprio(1);
#pragma unroll
    for (int ks = 0; ks < 2; ks++) {
      bf16x8 aw = *(const bf16x8*)(wrow + ((64 * ks + 16 * lq) ^ ((lr & 7) << 4)));
#pragma unroll
      for (int fn = 0; fn < 4; fn++) {
        int row = 16 * fn + lr;
        bf16x8 bv = *(const bf16x8*)((const char*)&sKV[1][wg][0] + row * 128 +
                                     ((64 * ks + 16 * lq) ^ ((row & 7) << 4)));
        num[fn] = MFMA16(aw, bv, num[fn]);
      }
    }
    __builtin_amdgcn_s_setprio(0);
    __syncthreads();  // everyone done reading sKV before next stage overwrites
  }

  // combine partials: den via sDen, num via LDS exchange (reuse sKV, 32KB)
  den += __shfl_xor(den, 16);
  den += __shfl_xor(den, 32);
  if (lq == 0) sDen[w][lr] = den;
  float* xch = (float*)&sKV[0][0][0];
  if (wg == 1) {
#pragma unroll
    for (int fn = 0; fn < 4; fn++)
      *(f32x4*)&xch[((size_t)(wq * 64 + lane)) * 16 + fn * 4] = num[fn];
  }
  __syncthreads();

  if (wg == 0) {
#pragma unroll
    for (int fn = 0; fn < 4; fn++)
      num[fn] += *(const f32x4*)&xch[((size_t)(wq * 64 + lane)) * 16 + fn * 4];

    f32x4 dv = *(const f32x4*)&sDen[wq][4 * lq];
    f32x4 dv2 = *(const f32x4*)&sDen[wq + 8][4 * lq];
    f32x4 rdv;
#pragma unroll
    for (int r = 0; r < 4; r++)
      rdv[r] = __builtin_amdgcn_rcpf(dv[r] + dv2[r] + SHEP_EPS);

    // epilogue: gate with G and store bf16 O
    const unsigned short* gbase = qbase + 192;
#pragma unroll
    for (int fn = 0; fn < 4; fn++) {
      int c = 16 * fn + lr;
#pragma unroll
      for (int r = 0; r < 4; r++) {
        int ql = 16 * wq + 4 * lq + r;
        float g = bf2f(gbase[(size_t)ql * PROW + c]);
        float a = num[fn][r] * rdv[r];
        O[((size_t)(b * SEQ + qt * 128 + ql)) * D_MODEL + h * DH + c] = f2bf(g * a);
      }
    }
  }
}

extern "C" void kernel_launch(void* const* d_in, const int* in_sizes, int n_in,
                              void* d_out, int out_size, void* d_ws, size_t ws_size,
                              hipStream_t stream) {
  const float* X = (const float*)d_in[0];
  const float* W_in = (const float*)d_in[1];
  const float* b_in = (const float*)d_in[2];
  const float* W_out = (const float*)d_in[3];
  const float* b_out = (const float*)d_in[4];
  float* out = (float*)d_out;

  // ws layout:
  //   [0,8MB):    Xn (bf16)        -> reused as O (gated attn output, bf16)
  //   [8,16MB):   Wi bf16          -> reused as Vt (transposed V, bf16)
  //   [16,18MB):  Wo bf16
  //   [18,50MB):  P = QKVG (bf16, [4096][4096])
  //   [50MB,+512K): q2/k2 norms (f32)
  char* ws = (char*)d_ws;
  unsigned short* Xn = (unsigned short*)(ws);
  unsigned short* O = (unsigned short*)(ws);
  unsigned short* Wi = (unsigned short*)(ws + ((size_t)8 << 20));
  unsigned short* Vt = (unsigned short*)(ws + ((size_t)8 << 20));
  unsigned short* Wo = (unsigned short*)(ws + ((size_t)16 << 20));
  unsigned short* P = (unsigned short*)(ws + ((size_t)18 << 20));
  float* nrm = (float*)(ws + ((size_t)50 << 20));

  ln_kernel<<<NTOK, 256, 0, stream>>>(X, Xn);
  cvt_bf16_kernel<<<4096, 256, 0, stream>>>(W_in, Wi, (4096 * 1024) / 4);
  cvt_bf16_kernel<<<1024, 256, 0, stream>>>(W_out, Wo, (1024 * 1024) / 4);
  gemm_p_kernel<<<dim3(32, 32), 256, 0, stream>>>(Xn, Wi, b_in, P, 4096, 4096, 1024);
  transv_kernel<<<dim3(32, 32), 256, 0, stream>>>(P, Vt);
  norms_kernel<<<512, 256, 0, stream>>>(P, nrm);
  attn_kernel<<<dim3(16, 32), 1024, 0, stream>>>(P, Vt, nrm, O);
  gemm_out_kernel<<<dim3(8, 32), 256, 0, stream>>>(O, Wo, b_out, X, out, 4096, 1024, 1024);
}

// Round 6
// 173.854 us; speedup vs baseline: 1.0267x; 1.0267x over previous
//
#include <hip/hip_runtime.h>

#define SEQ 2048
#define D_MODEL 1024
#define NTOK 4096
#define PROW 4096
#define DH 64
#define LN_EPS 1e-5f
#define SHEP_EPS 1e-4f

typedef __attribute__((ext_vector_type(8))) short bf16x8;
typedef __attribute__((ext_vector_type(4))) short s16x4;
typedef __attribute__((ext_vector_type(4))) float f32x4;

__device__ __forceinline__ unsigned short f2bf(float f) {
  union { float f; unsigned u; } v; v.f = f;
  unsigned r = v.u + 0x7fffu + ((v.u >> 16) & 1u);
  return (unsigned short)(r >> 16);
}
__device__ __forceinline__ float bf2f(unsigned short s) {
  union { unsigned u; float f; } v; v.u = ((unsigned)s) << 16;
  return v.f;
}
__device__ __forceinline__ void gload16(const void* g, void* l) {
  __builtin_amdgcn_global_load_lds(
      (const __attribute__((address_space(1))) unsigned int*)g,
      (__attribute__((address_space(3))) unsigned int*)l, 16, 0, 0);
}
__device__ __forceinline__ void gload4(const void* g, void* l) {
  __builtin_amdgcn_global_load_lds(
      (const __attribute__((address_space(1))) unsigned int*)g,
      (__attribute__((address_space(3))) unsigned int*)l, 4, 0, 0);
}
__device__ __forceinline__ unsigned cvt_pk_bf16(float lo, float hi) {
  unsigned r;
  asm("v_cvt_pk_bf16_f32 %0, %1, %2" : "=v"(r) : "v"(lo), "v"(hi));
  return r;
}
#define MFMA16(a, b, c) __builtin_amdgcn_mfma_f32_16x16x32_bf16(a, b, c, 0, 0, 0)

// ---------------- LayerNorm: f32 row -> bf16 row ----------------
__global__ __launch_bounds__(256) void ln_kernel(const float* __restrict__ X,
                                                 unsigned short* __restrict__ Xn) {
  int row = blockIdx.x, tid = threadIdx.x;
  const float4* xr = (const float4*)(X + (size_t)row * D_MODEL);
  float4 v = xr[tid];
  float s = v.x + v.y + v.z + v.w;
  float s2 = v.x * v.x + v.y * v.y + v.z * v.z + v.w * v.w;
#pragma unroll
  for (int off = 32; off > 0; off >>= 1) {
    s += __shfl_down(s, off);
    s2 += __shfl_down(s2, off);
  }
  __shared__ float red[8];
  __shared__ float mb[2];
  int wv = tid >> 6;
  if ((tid & 63) == 0) { red[wv] = s; red[4 + wv] = s2; }
  __syncthreads();
  if (tid == 0) {
    float ts = red[0] + red[1] + red[2] + red[3];
    float t2 = red[4] + red[5] + red[6] + red[7];
    float mu = ts * (1.f / D_MODEL);
    float var = t2 * (1.f / D_MODEL) - mu * mu;
    mb[0] = mu;
    mb[1] = rsqrtf(var + LN_EPS);
  }
  __syncthreads();
  float mu = mb[0], rs = mb[1];
  s16x4 o;
  o[0] = (short)f2bf((v.x - mu) * rs);
  o[1] = (short)f2bf((v.y - mu) * rs);
  o[2] = (short)f2bf((v.z - mu) * rs);
  o[3] = (short)f2bf((v.w - mu) * rs);
  ((s16x4*)(Xn + (size_t)row * D_MODEL))[tid] = o;
}

// ---------------- f32 -> bf16 convert (weights) ----------------
__global__ __launch_bounds__(256) void cvt_bf16_kernel(const float* __restrict__ in,
                                                       unsigned short* __restrict__ out,
                                                       int n4) {
  int i = blockIdx.x * 256 + threadIdx.x;
  if (i >= n4) return;
  float4 v = ((const float4*)in)[i];
  s16x4 o;
  o[0] = (short)f2bf(v.x);
  o[1] = (short)f2bf(v.y);
  o[2] = (short)f2bf(v.z);
  o[3] = (short)f2bf(v.w);
  ((s16x4*)out)[i] = o;
}

// ---------------- GEMM (NT, bf16 in, bf16 out + bias) : P = Xn*Wi^T + b ----------------
__global__ __launch_bounds__(256) void gemm_p_kernel(
    const unsigned short* __restrict__ A, const unsigned short* __restrict__ B,
    const float* __restrict__ bias, unsigned short* __restrict__ C,
    int M, int N, int K) {
  __shared__ __align__(16) unsigned short sA[128 * 32];
  __shared__ __align__(16) unsigned short sB[128 * 32];
  int tid = threadIdx.x;
  int m0 = blockIdx.y * 128, n0 = blockIdx.x * 128;
  int wv = tid >> 6, lane = tid & 63;
  int wr = wv >> 1, wc = wv & 1;
  int lr = lane & 15, lq = lane >> 4;
  f32x4 acc[4][4] = {};
  int srow = tid >> 2, scol = (tid & 3) * 8;
  const unsigned short* gA = A + (size_t)(m0 + srow) * K + scol;
  const unsigned short* gB = B + (size_t)(n0 + srow) * K + scol;
  unsigned short* lA = sA + tid * 8;
  unsigned short* lB = sB + tid * 8;
  for (int k0 = 0; k0 < K; k0 += 32) {
    gload16(gA + k0, lA);
    gload16(gA + k0 + (size_t)64 * K, lA + 64 * 32);
    gload16(gB + k0, lB);
    gload16(gB + k0 + (size_t)64 * K, lB + 64 * 32);
    __syncthreads();
    bf16x8 af[4], bfr[4];
#pragma unroll
    for (int m = 0; m < 4; m++)
      af[m] = *(const bf16x8*)&sA[(wr * 64 + m * 16 + lr) * 32 + lq * 8];
#pragma unroll
    for (int n = 0; n < 4; n++)
      bfr[n] = *(const bf16x8*)&sB[(wc * 64 + n * 16 + lr) * 32 + lq * 8];
#pragma unroll
    for (int m = 0; m < 4; m++)
#pragma unroll
      for (int n = 0; n < 4; n++)
        acc[m][n] = MFMA16(af[m], bfr[n], acc[m][n]);
    __syncthreads();
  }
#pragma unroll
  for (int m = 0; m < 4; m++) {
    int row = m0 + wr * 64 + m * 16 + lq * 4;
#pragma unroll
    for (int n = 0; n < 4; n++) {
      int col = n0 + wc * 64 + n * 16 + lr;
      float bv = bias[col];
#pragma unroll
      for (int r = 0; r < 4; r++)
        C[(size_t)(row + r) * N + col] = f2bf(acc[m][n][r] + bv);
    }
  }
}

// ---------------- GEMM (NT) + residual + bias, f32 out : out = X + O*Wo^T + b ----------------
__global__ __launch_bounds__(256) void gemm_out_kernel(
    const unsigned short* __restrict__ A, const unsigned short* __restrict__ B,
    const float* __restrict__ bias, const float* __restrict__ Xres,
    float* __restrict__ Out, int M, int N, int K) {
  __shared__ __align__(16) unsigned short sA[128 * 32];
  __shared__ __align__(16) unsigned short sB[128 * 32];
  int tid = threadIdx.x;
  int m0 = blockIdx.y * 128, n0 = blockIdx.x * 128;
  int wv = tid >> 6, lane = tid & 63;
  int wr = wv >> 1, wc = wv & 1;
  int lr = lane & 15, lq = lane >> 4;
  f32x4 acc[4][4] = {};
  int srow = tid >> 2, scol = (tid & 3) * 8;
  const unsigned short* gA = A + (size_t)(m0 + srow) * K + scol;
  const unsigned short* gB = B + (size_t)(n0 + srow) * K + scol;
  unsigned short* lA = sA + tid * 8;
  unsigned short* lB = sB + tid * 8;
  for (int k0 = 0; k0 < K; k0 += 32) {
    gload16(gA + k0, lA);
    gload16(gA + k0 + (size_t)64 * K, lA + 64 * 32);
    gload16(gB + k0, lB);
    gload16(gB + k0 + (size_t)64 * K, lB + 64 * 32);
    __syncthreads();
    bf16x8 af[4], bfr[4];
#pragma unroll
    for (int m = 0; m < 4; m++)
      af[m] = *(const bf16x8*)&sA[(wr * 64 + m * 16 + lr) * 32 + lq * 8];
#pragma unroll
    for (int n = 0; n < 4; n++)
      bfr[n] = *(const bf16x8*)&sB[(wc * 64 + n * 16 + lr) * 32 + lq * 8];
#pragma unroll
    for (int m = 0; m < 4; m++)
#pragma unroll
      for (int n = 0; n < 4; n++)
        acc[m][n] = MFMA16(af[m], bfr[n], acc[m][n]);
    __syncthreads();
  }
#pragma unroll
  for (int m = 0; m < 4; m++) {
    int row = m0 + wr * 64 + m * 16 + lq * 4;
#pragma unroll
    for (int n = 0; n < 4; n++) {
      int col = n0 + wc * 64 + n * 16 + lr;
      float bv = bias[col];
#pragma unroll
      for (int r = 0; r < 4; r++) {
        size_t idx = (size_t)(row + r) * N + col;
        Out[idx] = Xres[idx] + acc[m][n][r] + bv;
      }
    }
  }
}

// ---------------- V transpose: P's V slice [t][c] -> Vt[bh][c][t] ----------------
__global__ __launch_bounds__(256) void transv_kernel(const unsigned short* __restrict__ P,
                                                     unsigned short* __restrict__ Vt) {
  int kt = blockIdx.x;  // t-tile of 64
  int bh = blockIdx.y;
  int b = bh >> 4, h = bh & 15;
  __shared__ unsigned short sT[64][72];  // [c][k]
  int tid = threadIdx.x;
  const unsigned short* vbase = P + ((size_t)(b * SEQ + kt * 64)) * PROW + h * 256 + 128;
#pragma unroll
  for (int it = 0; it < 2; it++) {
    int c = tid + it * 256;
    int k = c >> 3, c0 = (c & 7) * 8;
    uint4 u = *(const uint4*)(vbase + (size_t)k * PROW + c0);
    unsigned e[4] = {u.x, u.y, u.z, u.w};
#pragma unroll
    for (int j = 0; j < 4; j++) {
      sT[c0 + 2 * j][k] = (unsigned short)(e[j] & 0xffffu);
      sT[c0 + 2 * j + 1][k] = (unsigned short)(e[j] >> 16);
    }
  }
  __syncthreads();
  unsigned short* obase = Vt + (size_t)bh * 64 * SEQ + kt * 64;
#pragma unroll
  for (int it = 0; it < 2; it++) {
    int cc = tid + it * 256;
    int crow = cc >> 3, k0 = (cc & 7) * 8;
    uint4 o;
    unsigned short e[8];
#pragma unroll
    for (int j = 0; j < 8; j++) e[j] = sT[crow][k0 + j];
    o.x = (unsigned)e[0] | ((unsigned)e[1] << 16);
    o.y = (unsigned)e[2] | ((unsigned)e[3] << 16);
    o.z = (unsigned)e[4] | ((unsigned)e[5] << 16);
    o.w = (unsigned)e[6] | ((unsigned)e[7] << 16);
    *(uint4*)(obase + (size_t)crow * SEQ + k0) = o;
  }
}

// ---------------- row norms of Q and K slices (from bf16 P) ----------------
__global__ __launch_bounds__(256) void norms_kernel(const unsigned short* __restrict__ P,
                                                    float* __restrict__ nrm) {
  int id = blockIdx.x * 256 + threadIdx.x;  // 32*2*2048
  int bh = id >> 12;
  int which = (id >> 11) & 1;
  int t = id & 2047;
  int b = bh >> 4, h = bh & 15;
  const unsigned short* p = P + ((size_t)(b * SEQ + t)) * PROW + h * 256 + which * 64;
  const uint4* pv = (const uint4*)p;
  float acc = 0.f;
#pragma unroll
  for (int i = 0; i < 8; i++) {
    uint4 u = pv[i];
    unsigned arr[4] = {u.x, u.y, u.z, u.w};
#pragma unroll
    for (int j = 0; j < 4; j++) {
      float lo = __uint_as_float(arr[j] << 16);
      float hi = __uint_as_float(arr[j] & 0xffff0000u);
      acc += lo * lo + hi * hi;
    }
  }
  nrm[(size_t)(bh * 2 + which) * SEQ + t] = acc;
}

// ---------------- Shepard attention (4 waves x 32 q-rows) -- BISECT BUILD ----------------
// Identical to the round-5 kernel EXCEPT den: the MFMA-with-all-ones dacc is
// replaced by the round-2-proven shuffle+sDen path. Controlled single-variable
// test: pass => dacc trick was the bug; fail => 4-wave geometry is the bug.
__global__ __launch_bounds__(256) void attn_kernel(
    const unsigned short* __restrict__ P, const unsigned short* __restrict__ Vt,
    const float* __restrict__ nrm, unsigned short* __restrict__ O) {
  const int NT = SEQ / 64;  // 32
  int qt = blockIdx.x, bh = blockIdx.y;
  int b = bh >> 4, h = bh & 15;
  int tid = threadIdx.x;
  int w = tid >> 6, lane = tid & 63;
  int lr = lane & 15, lq = lane >> 4;

  __shared__ __align__(16) unsigned short sQ[128 * 64];
  __shared__ __align__(16) unsigned short sK[2][64 * 64];
  __shared__ __align__(16) unsigned short sV[2][64 * 64];
  __shared__ __align__(16) unsigned short sW[128 * 64];  // wave-private 32-row slabs
  __shared__ __align__(16) float sK2[2][64];
  __shared__ __align__(16) float sDen[4][2][16];

  const unsigned short* qbase = P + ((size_t)(b * SEQ + qt * 128)) * PROW + h * 256;
  const unsigned short* kbase = P + ((size_t)(b * SEQ)) * PROW + h * 256 + 64;
  const unsigned short* vtb = Vt + (size_t)bh * 64 * SEQ;
  const float* k2base = nrm + (size_t)(bh * 2 + 1) * SEQ;

  auto stage_kv = [&](int t, int buf) {
#pragma unroll
    for (int it = 0; it < 2; it++) {
      int c = tid + it * 256;
      int row = c >> 3;
      int col = ((c & 7) ^ (row & 7)) * 8;
      gload16(kbase + (size_t)(t * 64 + row) * PROW + col, (char*)&sK[buf][0] + c * 16);
      gload16(vtb + (size_t)row * SEQ + t * 64 + col, (char*)&sV[buf][0] + c * 16);
    }
    if (tid < 64) gload4(k2base + t * 64 + tid, (char*)&sK2[buf][0] + tid * 4);
  };

  // ---- prologue: stage Q + tile 0; load q2; one full drain
#pragma unroll
  for (int it = 0; it < 4; it++) {
    int c = tid + it * 256;
    int row = c >> 3;
    int col = ((c & 7) ^ (row & 7)) * 8;
    gload16(qbase + (size_t)row * PROW + col, (char*)sQ + c * 16);
  }
  stage_kv(0, 0);
  float q2f0 = nrm[(size_t)(bh * 2) * SEQ + qt * 128 + 32 * w + lr];
  float q2f1 = nrm[(size_t)(bh * 2) * SEQ + qt * 128 + 32 * w + 16 + lr];
  __syncthreads();

  // hoist Q fragments (B-operand of S^T = K.Q^T)
  bf16x8 qf[2][2];
#pragma unroll
  for (int fq = 0; fq < 2; fq++) {
    int row = 32 * w + 16 * fq + lr;
#pragma unroll
    for (int ks = 0; ks < 2; ks++)
      qf[fq][ks] = *(const bf16x8*)((const char*)sQ + row * 128 +
                                    ((ks * 64 + lq * 16) ^ ((row & 7) << 4)));
  }

  f32x4 num[2][4] = {};
  float den[2] = {0.f, 0.f};
  char* wrow0 = (char*)sW + (32 * w + lr) * 128;
  char* wrow1 = (char*)sW + (32 * w + 16 + lr) * 128;

  for (int t = 0; t < NT; t++) {
    int cur = t & 1;
    // stage NEXT tile into the other buffer; latency hides under this phase's
    // compute; end-of-phase __syncthreads (vmcnt0+lgkm0+barrier) publishes it.
    if (t + 1 < NT) stage_kv(t + 1, cur ^ 1);

    // S^T[k][q] = K . Q^T (K fragments shared across both q-frags)
    f32x4 st[2][4] = {};
    __builtin_amdgcn_s_setprio(1);
#pragma unroll
    for (int fk = 0; fk < 4; fk++) {
      int row = 16 * fk + lr;
      const char* krow = (const char*)&sK[cur][0] + row * 128;
      bf16x8 kf0 = *(const bf16x8*)(krow + ((lq * 16) ^ ((row & 7) << 4)));
      bf16x8 kf1 = *(const bf16x8*)(krow + ((64 + lq * 16) ^ ((row & 7) << 4)));
      st[0][fk] = MFMA16(kf0, qf[0][0], st[0][fk]);
      st[0][fk] = MFMA16(kf1, qf[0][1], st[0][fk]);
      st[1][fk] = MFMA16(kf0, qf[1][0], st[1][fk]);
      st[1][fk] = MFMA16(kf1, qf[1][1], st[1][fk]);
    }
    __builtin_amdgcn_s_setprio(0);

    // weights: w = rcp(max(q2+k2-2*st, 1e-8)); accumulate den; pack bf16 to W slab
#pragma unroll
    for (int fk = 0; fk < 4; fk++) {
      f32x4 k2v = *(const f32x4*)&sK2[cur][16 * fk + 4 * lq];
#pragma unroll
      for (int fq = 0; fq < 2; fq++) {
        float q2 = fq ? q2f1 : q2f0;
        float w0 = __builtin_amdgcn_rcpf(fmaxf(fmaf(-2.f, st[fq][fk][0], q2 + k2v[0]), 1e-8f));
        float w1 = __builtin_amdgcn_rcpf(fmaxf(fmaf(-2.f, st[fq][fk][1], q2 + k2v[1]), 1e-8f));
        float w2 = __builtin_amdgcn_rcpf(fmaxf(fmaf(-2.f, st[fq][fk][2], q2 + k2v[2]), 1e-8f));
        float w3 = __builtin_amdgcn_rcpf(fmaxf(fmaf(-2.f, st[fq][fk][3], q2 + k2v[3]), 1e-8f));
        den[fq] += (w0 + w1) + (w2 + w3);
        uint2 pp;
        pp.x = cvt_pk_bf16(w0, w1);
        pp.y = cvt_pk_bf16(w2, w3);
        char* wr = fq ? wrow1 : wrow0;
        *(uint2*)(wr + ((32 * fk + 8 * lq) ^ ((lr & 7) << 4))) = pp;
      }
    }

    // PV: num += W.V^T (V fragments shared across q-frags)
    __builtin_amdgcn_s_setprio(1);
#pragma unroll
    for (int ks = 0; ks < 2; ks++) {
      bf16x8 aw0 = *(const bf16x8*)(wrow0 + ((64 * ks + 16 * lq) ^ ((lr & 7) << 4)));
      bf16x8 aw1 = *(const bf16x8*)(wrow1 + ((64 * ks + 16 * lq) ^ ((lr & 7) << 4)));
#pragma unroll
      for (int fn = 0; fn < 4; fn++) {
        int row = 16 * fn + lr;
        bf16x8 bv = *(const bf16x8*)((const char*)&sV[cur][0] + row * 128 +
                                     ((64 * ks + 16 * lq) ^ ((row & 7) << 4)));
        num[0][fn] = MFMA16(aw0, bv, num[0][fn]);
        num[1][fn] = MFMA16(aw1, bv, num[1][fn]);
      }
    }
    __builtin_amdgcn_s_setprio(0);

    __syncthreads();  // publishes tile t+1; all reads of tile t complete
  }

  // den: lanes with same lr hold the 4 lq-partials for q=...+lr; sum them,
  // then LDS round-trip to re-index den by q-local 4lq+r (num's row mapping).
#pragma unroll
  for (int fq = 0; fq < 2; fq++) {
    den[fq] += __shfl_xor(den[fq], 16);
    den[fq] += __shfl_xor(den[fq], 32);
  }
  if (lq == 0) {
    sDen[w][0][lr] = den[0];
    sDen[w][1][lr] = den[1];
  }
  __syncthreads();

  // epilogue: rdv from sDen, gate with G, store bf16 O
  const unsigned short* gbase = qbase + 192;
#pragma unroll
  for (int fq = 0; fq < 2; fq++) {
    f32x4 dv = *(const f32x4*)&sDen[w][fq][4 * lq];
    f32x4 rdv;
#pragma unroll
    for (int r = 0; r < 4; r++)
      rdv[r] = __builtin_amdgcn_rcpf(dv[r] + SHEP_EPS);
#pragma unroll
    for (int fn = 0; fn < 4; fn++) {
      int c = 16 * fn + lr;
#pragma unroll
      for (int r = 0; r < 4; r++) {
        int ql = 32 * w + 16 * fq + 4 * lq + r;
        float g = bf2f(gbase[(size_t)ql * PROW + c]);
        O[((size_t)(b * SEQ + qt * 128 + ql)) * D_MODEL + h * DH + c] =
            f2bf(g * num[fq][fn][r] * rdv[r]);
      }
    }
  }
}

extern "C" void kernel_launch(void* const* d_in, const int* in_sizes, int n_in,
                              void* d_out, int out_size, void* d_ws, size_t ws_size,
                              hipStream_t stream) {
  const float* X = (const float*)d_in[0];
  const float* W_in = (const float*)d_in[1];
  const float* b_in = (const float*)d_in[2];
  const float* W_out = (const float*)d_in[3];
  const float* b_out = (const float*)d_in[4];
  float* out = (float*)d_out;

  // ws layout:
  //   [0,8MB):    Xn (bf16)        -> reused as O (gated attn output, bf16)
  //   [8,16MB):   Wi bf16          -> reused as Vt (transposed V, bf16)
  //   [16,18MB):  Wo bf16
  //   [18,50MB):  P = QKVG (bf16, [4096][4096])
  //   [50MB,+512K): q2/k2 norms (f32)
  char* ws = (char*)d_ws;
  unsigned short* Xn = (unsigned short*)(ws);
  unsigned short* O = (unsigned short*)(ws);
  unsigned short* Wi = (unsigned short*)(ws + ((size_t)8 << 20));
  unsigned short* Vt = (unsigned short*)(ws + ((size_t)8 << 20));
  unsigned short* Wo = (unsigned short*)(ws + ((size_t)16 << 20));
  unsigned short* P = (unsigned short*)(ws + ((size_t)18 << 20));
  float* nrm = (float*)(ws + ((size_t)50 << 20));

  ln_kernel<<<NTOK, 256, 0, stream>>>(X, Xn);
  cvt_bf16_kernel<<<4096, 256, 0, stream>>>(W_in, Wi, (4096 * 1024) / 4);
  cvt_bf16_kernel<<<1024, 256, 0, stream>>>(W_out, Wo, (1024 * 1024) / 4);
  gemm_p_kernel<<<dim3(32, 32), 256, 0, stream>>>(Xn, Wi, b_in, P, 4096, 4096, 1024);
  transv_kernel<<<dim3(32, 32), 256, 0, stream>>>(P, Vt);
  norms_kernel<<<512, 256, 0, stream>>>(P, nrm);
  attn_kernel<<<dim3(16, 32), 256, 0, stream>>>(P, Vt, nrm, O);
  gemm_out_kernel<<<dim3(8, 32), 256, 0, stream>>>(O, Wo, b_out, X, out, 4096, 1024, 1024);
}

// Round 7
// 170.311 us; speedup vs baseline: 1.0481x; 1.0208x over previous
//
#include <hip/hip_runtime.h>

#define SEQ 2048
#define D_MODEL 1024
#define NTOK 4096
#define PROW 4096
#define DH 64
#define LN_EPS 1e-5f
#define SHEP_EPS 1e-4f

typedef __attribute__((ext_vector_type(8))) short bf16x8;
typedef __attribute__((ext_vector_type(4))) short s16x4;
typedef __attribute__((ext_vector_type(4))) float f32x4;

__device__ __forceinline__ unsigned short f2bf(float f) {
  union { float f; unsigned u; } v; v.f = f;
  unsigned r = v.u + 0x7fffu + ((v.u >> 16) & 1u);
  return (unsigned short)(r >> 16);
}
__device__ __forceinline__ float bf2f(unsigned short s) {
  union { unsigned u; float f; } v; v.u = ((unsigned)s) << 16;
  return v.f;
}
__device__ __forceinline__ void gload16(const void* g, void* l) {
  __builtin_amdgcn_global_load_lds(
      (const __attribute__((address_space(1))) unsigned int*)g,
      (__attribute__((address_space(3))) unsigned int*)l, 16, 0, 0);
}
__device__ __forceinline__ void gload4(const void* g, void* l) {
  __builtin_amdgcn_global_load_lds(
      (const __attribute__((address_space(1))) unsigned int*)g,
      (__attribute__((address_space(3))) unsigned int*)l, 4, 0, 0);
}
__device__ __forceinline__ unsigned cvt_pk_bf16(float lo, float hi) {
  unsigned r;
  asm("v_cvt_pk_bf16_f32 %0, %1, %2" : "=v"(r) : "v"(lo), "v"(hi));
  return r;
}
#define MFMA16(a, b, c) __builtin_amdgcn_mfma_f32_16x16x32_bf16(a, b, c, 0, 0, 0)

// XCD-aware bijective block swizzle (T1): valid since nwg % 8 == 0.
__device__ __forceinline__ int xcd_swizzle(int linear, int nwg) {
  int cpx = nwg >> 3;
  return (linear & 7) * cpx + (linear >> 3);
}

// ---------------- LayerNorm: f32 row -> bf16 row ----------------
__global__ __launch_bounds__(256) void ln_kernel(const float* __restrict__ X,
                                                 unsigned short* __restrict__ Xn) {
  int row = blockIdx.x, tid = threadIdx.x;
  const float4* xr = (const float4*)(X + (size_t)row * D_MODEL);
  float4 v = xr[tid];
  float s = v.x + v.y + v.z + v.w;
  float s2 = v.x * v.x + v.y * v.y + v.z * v.z + v.w * v.w;
#pragma unroll
  for (int off = 32; off > 0; off >>= 1) {
    s += __shfl_down(s, off);
    s2 += __shfl_down(s2, off);
  }
  __shared__ float red[8];
  __shared__ float mb[2];
  int wv = tid >> 6;
  if ((tid & 63) == 0) { red[wv] = s; red[4 + wv] = s2; }
  __syncthreads();
  if (tid == 0) {
    float ts = red[0] + red[1] + red[2] + red[3];
    float t2 = red[4] + red[5] + red[6] + red[7];
    float mu = ts * (1.f / D_MODEL);
    float var = t2 * (1.f / D_MODEL) - mu * mu;
    mb[0] = mu;
    mb[1] = rsqrtf(var + LN_EPS);
  }
  __syncthreads();
  float mu = mb[0], rs = mb[1];
  s16x4 o;
  o[0] = (short)f2bf((v.x - mu) * rs);
  o[1] = (short)f2bf((v.y - mu) * rs);
  o[2] = (short)f2bf((v.z - mu) * rs);
  o[3] = (short)f2bf((v.w - mu) * rs);
  ((s16x4*)(Xn + (size_t)row * D_MODEL))[tid] = o;
}

// ---------------- fused f32 -> bf16 convert (W_in then W_out, contiguous dest) ----------------
__global__ __launch_bounds__(256) void cvt_both_kernel(const float* __restrict__ Win,
                                                       const float* __restrict__ Wout,
                                                       unsigned short* __restrict__ dst) {
  const int N1 = (4096 * 1024) / 4;       // W_in float4 count
  const int N2 = (1024 * 1024) / 4;       // W_out float4 count
  int i = blockIdx.x * 256 + threadIdx.x;
  if (i >= N1 + N2) return;
  float4 v = (i < N1) ? ((const float4*)Win)[i] : ((const float4*)Wout)[i - N1];
  s16x4 o;
  o[0] = (short)f2bf(v.x);
  o[1] = (short)f2bf(v.y);
  o[2] = (short)f2bf(v.z);
  o[3] = (short)f2bf(v.w);
  ((s16x4*)dst)[i] = o;
}

// ---------------- GEMM (NT, bf16 in, bf16 out + bias) : P = Xn*Wi^T + b ----------------
__global__ __launch_bounds__(256) void gemm_p_kernel(
    const unsigned short* __restrict__ A, const unsigned short* __restrict__ B,
    const float* __restrict__ bias, unsigned short* __restrict__ C,
    int M, int N, int K) {
  __shared__ __align__(16) unsigned short sA[128 * 32];
  __shared__ __align__(16) unsigned short sB[128 * 32];
  int tid = threadIdx.x;
  int nwg = gridDim.x * gridDim.y;
  int swz = xcd_swizzle(blockIdx.y * gridDim.x + blockIdx.x, nwg);
  int m0 = (swz / gridDim.x) * 128, n0 = (swz % gridDim.x) * 128;
  int wv = tid >> 6, lane = tid & 63;
  int wr = wv >> 1, wc = wv & 1;
  int lr = lane & 15, lq = lane >> 4;
  f32x4 acc[4][4] = {};
  int srow = tid >> 2, scol = (tid & 3) * 8;
  const unsigned short* gA = A + (size_t)(m0 + srow) * K + scol;
  const unsigned short* gB = B + (size_t)(n0 + srow) * K + scol;
  unsigned short* lA = sA + tid * 8;
  unsigned short* lB = sB + tid * 8;
  for (int k0 = 0; k0 < K; k0 += 32) {
    gload16(gA + k0, lA);
    gload16(gA + k0 + (size_t)64 * K, lA + 64 * 32);
    gload16(gB + k0, lB);
    gload16(gB + k0 + (size_t)64 * K, lB + 64 * 32);
    __syncthreads();
    bf16x8 af[4], bfr[4];
#pragma unroll
    for (int m = 0; m < 4; m++)
      af[m] = *(const bf16x8*)&sA[(wr * 64 + m * 16 + lr) * 32 + lq * 8];
#pragma unroll
    for (int n = 0; n < 4; n++)
      bfr[n] = *(const bf16x8*)&sB[(wc * 64 + n * 16 + lr) * 32 + lq * 8];
#pragma unroll
    for (int m = 0; m < 4; m++)
#pragma unroll
      for (int n = 0; n < 4; n++)
        acc[m][n] = MFMA16(af[m], bfr[n], acc[m][n]);
    __syncthreads();
  }
#pragma unroll
  for (int m = 0; m < 4; m++) {
    int row = m0 + wr * 64 + m * 16 + lq * 4;
#pragma unroll
    for (int n = 0; n < 4; n++) {
      int col = n0 + wc * 64 + n * 16 + lr;
      float bv = bias[col];
#pragma unroll
      for (int r = 0; r < 4; r++)
        C[(size_t)(row + r) * N + col] = f2bf(acc[m][n][r] + bv);
    }
  }
}

// ---------------- GEMM (NT) + residual + bias, f32 out : out = X + O*Wo^T + b ----------------
__global__ __launch_bounds__(256) void gemm_out_kernel(
    const unsigned short* __restrict__ A, const unsigned short* __restrict__ B,
    const float* __restrict__ bias, const float* __restrict__ Xres,
    float* __restrict__ Out, int M, int N, int K) {
  __shared__ __align__(16) unsigned short sA[128 * 32];
  __shared__ __align__(16) unsigned short sB[128 * 32];
  int tid = threadIdx.x;
  int nwg = gridDim.x * gridDim.y;
  int swz = xcd_swizzle(blockIdx.y * gridDim.x + blockIdx.x, nwg);
  int m0 = (swz / gridDim.x) * 128, n0 = (swz % gridDim.x) * 128;
  int wv = tid >> 6, lane = tid & 63;
  int wr = wv >> 1, wc = wv & 1;
  int lr = lane & 15, lq = lane >> 4;
  f32x4 acc[4][4] = {};
  int srow = tid >> 2, scol = (tid & 3) * 8;
  const unsigned short* gA = A + (size_t)(m0 + srow) * K + scol;
  const unsigned short* gB = B + (size_t)(n0 + srow) * K + scol;
  unsigned short* lA = sA + tid * 8;
  unsigned short* lB = sB + tid * 8;
  for (int k0 = 0; k0 < K; k0 += 32) {
    gload16(gA + k0, lA);
    gload16(gA + k0 + (size_t)64 * K, lA + 64 * 32);
    gload16(gB + k0, lB);
    gload16(gB + k0 + (size_t)64 * K, lB + 64 * 32);
    __syncthreads();
    bf16x8 af[4], bfr[4];
#pragma unroll
    for (int m = 0; m < 4; m++)
      af[m] = *(const bf16x8*)&sA[(wr * 64 + m * 16 + lr) * 32 + lq * 8];
#pragma unroll
    for (int n = 0; n < 4; n++)
      bfr[n] = *(const bf16x8*)&sB[(wc * 64 + n * 16 + lr) * 32 + lq * 8];
#pragma unroll
    for (int m = 0; m < 4; m++)
#pragma unroll
      for (int n = 0; n < 4; n++)
        acc[m][n] = MFMA16(af[m], bfr[n], acc[m][n]);
    __syncthreads();
  }
#pragma unroll
  for (int m = 0; m < 4; m++) {
    int row = m0 + wr * 64 + m * 16 + lq * 4;
#pragma unroll
    for (int n = 0; n < 4; n++) {
      int col = n0 + wc * 64 + n * 16 + lr;
      float bv = bias[col];
#pragma unroll
      for (int r = 0; r < 4; r++) {
        size_t idx = (size_t)(row + r) * N + col;
        Out[idx] = Xres[idx] + acc[m][n][r] + bv;
      }
    }
  }
}

// ---------------- V transpose: P's V slice [t][c] -> Vt[bh][c][t] ----------------
__global__ __launch_bounds__(256) void transv_kernel(const unsigned short* __restrict__ P,
                                                     unsigned short* __restrict__ Vt) {
  int kt = blockIdx.x;  // t-tile of 64
  int bh = blockIdx.y;
  int b = bh >> 4, h = bh & 15;
  __shared__ unsigned short sT[64][72];  // [c][k]
  int tid = threadIdx.x;
  const unsigned short* vbase = P + ((size_t)(b * SEQ + kt * 64)) * PROW + h * 256 + 128;
#pragma unroll
  for (int it = 0; it < 2; it++) {
    int c = tid + it * 256;
    int k = c >> 3, c0 = (c & 7) * 8;
    uint4 u = *(const uint4*)(vbase + (size_t)k * PROW + c0);
    unsigned e[4] = {u.x, u.y, u.z, u.w};
#pragma unroll
    for (int j = 0; j < 4; j++) {
      sT[c0 + 2 * j][k] = (unsigned short)(e[j] & 0xffffu);
      sT[c0 + 2 * j + 1][k] = (unsigned short)(e[j] >> 16);
    }
  }
  __syncthreads();
  unsigned short* obase = Vt + (size_t)bh * 64 * SEQ + kt * 64;
#pragma unroll
  for (int it = 0; it < 2; it++) {
    int cc = tid + it * 256;
    int crow = cc >> 3, k0 = (cc & 7) * 8;
    uint4 o;
    unsigned short e[8];
#pragma unroll
    for (int j = 0; j < 8; j++) e[j] = sT[crow][k0 + j];
    o.x = (unsigned)e[0] | ((unsigned)e[1] << 16);
    o.y = (unsigned)e[2] | ((unsigned)e[3] << 16);
    o.z = (unsigned)e[4] | ((unsigned)e[5] << 16);
    o.w = (unsigned)e[6] | ((unsigned)e[7] << 16);
    *(uint4*)(obase + (size_t)crow * SEQ + k0) = o;
  }
}

// ---------------- row norms of Q and K slices (from bf16 P) ----------------
__global__ __launch_bounds__(256) void norms_kernel(const unsigned short* __restrict__ P,
                                                    float* __restrict__ nrm) {
  int id = blockIdx.x * 256 + threadIdx.x;  // 32*2*2048
  int bh = id >> 12;
  int which = (id >> 11) & 1;
  int t = id & 2047;
  int b = bh >> 4, h = bh & 15;
  const unsigned short* p = P + ((size_t)(b * SEQ + t)) * PROW + h * 256 + which * 64;
  const uint4* pv = (const uint4*)p;
  float acc = 0.f;
#pragma unroll
  for (int i = 0; i < 8; i++) {
    uint4 u = pv[i];
    unsigned arr[4] = {u.x, u.y, u.z, u.w};
#pragma unroll
    for (int j = 0; j < 4; j++) {
      float lo = __uint_as_float(arr[j] << 16);
      float hi = __uint_as_float(arr[j] & 0xffff0000u);
      acc += lo * lo + hi * hi;
    }
  }
  nrm[(size_t)(bh * 2 + which) * SEQ + t] = acc;
}

// ---------------- Shepard attention (8 waves x 16 q-rows) -- r2-proven + setprio ----------------
// Exact round-2 structure (65.2us known-good): K/V time-double-buffered with
// prefetch at phase top; sW wave-private 16-row slabs; ONE __syncthreads per
// K-tile; den via shfl+sDen (r6-validated). Added: T5 setprio around the two
// MFMA clusters (attn-proven +4-7%).
__global__ __launch_bounds__(512) void attn_kernel(
    const unsigned short* __restrict__ P, const unsigned short* __restrict__ Vt,
    const float* __restrict__ nrm, unsigned short* __restrict__ O) {
  int qt = blockIdx.x, bh = blockIdx.y;
  int b = bh >> 4, h = bh & 15;
  int tid = threadIdx.x;
  int w = tid >> 6, lane = tid & 63;
  int lr = lane & 15, lq = lane >> 4;

  __shared__ __align__(16) unsigned short sQ[128 * 64];
  __shared__ __align__(16) unsigned short sK[2][64 * 64];
  __shared__ __align__(16) unsigned short sV[2][64 * 64];
  __shared__ __align__(16) unsigned short sW[128 * 64];  // wave-private 16-row slabs
  __shared__ __align__(16) float sK2[2][64];
  __shared__ __align__(16) float sDen[8][16];

  const unsigned short* qbase = P + ((size_t)(b * SEQ + qt * 128)) * PROW + h * 256;
  const unsigned short* kbase = P + ((size_t)(b * SEQ)) * PROW + h * 256 + 64;
  const unsigned short* vtb = Vt + (size_t)bh * 64 * SEQ;
  const float* k2base = nrm + (size_t)(bh * 2 + 1) * SEQ;

  // staging source addresses (pre-swizzled column)
  int srow = tid >> 3;
  int scol = ((tid & 7) ^ (srow & 7)) * 8;
  const unsigned short* kSrc = kbase + (size_t)srow * PROW + scol;
  const unsigned short* vSrc = vtb + (size_t)srow * SEQ + scol;

  // ---- prologue: stage Q, K/V tile 0, k2 tile 0
#pragma unroll
  for (int it = 0; it < 2; it++) {
    int c = tid + it * 512;
    int row = c >> 3;
    int col = ((c & 7) ^ (row & 7)) * 8;
    gload16(qbase + (size_t)row * PROW + col, (char*)sQ + c * 16);
  }
  gload16(kSrc, (char*)&sK[0][0] + tid * 16);
  gload16(vSrc, (char*)&sV[0][0] + tid * 16);
  if (w == 0) gload4(k2base + lane, (char*)&sK2[0][0] + lane * 4);
  float q2 = nrm[(size_t)(bh * 2) * SEQ + qt * 128 + 16 * w + lr];
  __syncthreads();

  // hoist Q fragments (B-operand of S^T = K.Q^T); sQ not touched again
  int qrow = 16 * w + lr;
  bf16x8 qf[2];
#pragma unroll
  for (int ks = 0; ks < 2; ks++)
    qf[ks] = *(const bf16x8*)((const char*)sQ + qrow * 128 +
                              ((ks * 64 + lq * 16) ^ ((lr & 7) << 4)));

  f32x4 num[4] = {};
  float den = 0.f;
  char* wrow = (char*)sW + qrow * 128;

  for (int kt = 0; kt < SEQ / 64; kt++) {
    int cur = kt & 1, nxt = cur ^ 1;
    // prefetch next K/V tile (drained by the barrier at the END of this phase)
    if (kt < SEQ / 64 - 1) {
      gload16(kSrc + (size_t)(kt + 1) * 64 * PROW, (char*)&sK[nxt][0] + tid * 16);
      gload16(vSrc + (size_t)(kt + 1) * 64, (char*)&sV[nxt][0] + tid * 16);
      if (w == 0) gload4(k2base + (kt + 1) * 64 + lane, (char*)&sK2[nxt][0] + lane * 4);
    }

    // S^T[k][q] = K . Q^T
    f32x4 st[4] = {};
    __builtin_amdgcn_s_setprio(1);
#pragma unroll
    for (int fk = 0; fk < 4; fk++) {
      int row = 16 * fk + lr;
      const char* krow = (const char*)&sK[cur][0] + row * 128;
      bf16x8 kf0 = *(const bf16x8*)(krow + ((lq * 16) ^ ((row & 7) << 4)));
      bf16x8 kf1 = *(const bf16x8*)(krow + ((64 + lq * 16) ^ ((row & 7) << 4)));
      st[fk] = MFMA16(kf0, qf[0], st[fk]);
      st[fk] = MFMA16(kf1, qf[1], st[fk]);
    }
    __builtin_amdgcn_s_setprio(0);

    // weights: w = rcp(max(q2+k2-2*st, 1e-8)); pack bf16 pairs; stash in sW
#pragma unroll
    for (int fk = 0; fk < 4; fk++) {
      f32x4 k2v = *(const f32x4*)&sK2[cur][16 * fk + 4 * lq];
      float w0 = __builtin_amdgcn_rcpf(fmaxf(fmaf(-2.f, st[fk][0], q2 + k2v[0]), 1e-8f));
      float w1 = __builtin_amdgcn_rcpf(fmaxf(fmaf(-2.f, st[fk][1], q2 + k2v[1]), 1e-8f));
      float w2 = __builtin_amdgcn_rcpf(fmaxf(fmaf(-2.f, st[fk][2], q2 + k2v[2]), 1e-8f));
      float w3 = __builtin_amdgcn_rcpf(fmaxf(fmaf(-2.f, st[fk][3], q2 + k2v[3]), 1e-8f));
      den += (w0 + w1) + (w2 + w3);
      uint2 pp;
      pp.x = cvt_pk_bf16(w0, w1);
      pp.y = cvt_pk_bf16(w2, w3);
      *(uint2*)(wrow + ((32 * fk + 8 * lq) ^ ((lr & 7) << 4))) = pp;
    }

    // PV: num[c] += W . V^T  (sW rows are this wave's own -> no barrier needed)
    __builtin_amdgcn_s_setprio(1);
#pragma unroll
    for (int ks = 0; ks < 2; ks++) {
      bf16x8 aw = *(const bf16x8*)(wrow + ((64 * ks + 16 * lq) ^ ((lr & 7) << 4)));
#pragma unroll
      for (int fn = 0; fn < 4; fn++) {
        int row = 16 * fn + lr;
        bf16x8 bv = *(const bf16x8*)((const char*)&sV[cur][0] + row * 128 +
                                     ((64 * ks + 16 * lq) ^ ((row & 7) << 4)));
        num[fn] = MFMA16(aw, bv, num[fn]);
      }
    }
    __builtin_amdgcn_s_setprio(0);
    __syncthreads();  // implicit vmcnt(0)+lgkmcnt(0): next tile staged & all reads done
  }

  // den: full sum over k lives split across the 4 lq-groups
  den += __shfl_xor(den, 16);
  den += __shfl_xor(den, 32);
  if (lq == 0) sDen[w][lr] = den;
  __syncthreads();
  f32x4 dv = *(const f32x4*)&sDen[w][4 * lq];
  f32x4 rdv;
#pragma unroll
  for (int r = 0; r < 4; r++) rdv[r] = __builtin_amdgcn_rcpf(dv[r] + SHEP_EPS);

  // epilogue: gate with G and store bf16 O
  const unsigned short* gbase = qbase + 192;
#pragma unroll
  for (int fn = 0; fn < 4; fn++) {
    int c = 16 * fn + lr;
#pragma unroll
    for (int r = 0; r < 4; r++) {
      int ql = 16 * w + 4 * lq + r;
      float g = bf2f(gbase[(size_t)ql * PROW + c]);
      float a = num[fn][r] * rdv[r];
      O[((size_t)(b * SEQ + qt * 128 + ql)) * D_MODEL + h * DH + c] = f2bf(g * a);
    }
  }
}

extern "C" void kernel_launch(void* const* d_in, const int* in_sizes, int n_in,
                              void* d_out, int out_size, void* d_ws, size_t ws_size,
                              hipStream_t stream) {
  const float* X = (const float*)d_in[0];
  const float* W_in = (const float*)d_in[1];
  const float* b_in = (const float*)d_in[2];
  const float* W_out = (const float*)d_in[3];
  const float* b_out = (const float*)d_in[4];
  float* out = (float*)d_out;

  // ws layout:
  //   [0,8MB):    Xn (bf16)        -> reused as O (gated attn output, bf16)
  //   [8,16MB):   Wi bf16          -> reused as Vt (transposed V, bf16)
  //   [16,18MB):  Wo bf16 (contiguous after Wi -> fused cvt)
  //   [18,50MB):  P = QKVG (bf16, [4096][4096])
  //   [50MB,+512K): q2/k2 norms (f32)
  char* ws = (char*)d_ws;
  unsigned short* Xn = (unsigned short*)(ws);
  unsigned short* O = (unsigned short*)(ws);
  unsigned short* Wi = (unsigned short*)(ws + ((size_t)8 << 20));
  unsigned short* Vt = (unsigned short*)(ws + ((size_t)8 << 20));
  unsigned short* Wo = (unsigned short*)(ws + ((size_t)16 << 20));
  unsigned short* P = (unsigned short*)(ws + ((size_t)18 << 20));
  float* nrm = (float*)(ws + ((size_t)50 << 20));

  ln_kernel<<<NTOK, 256, 0, stream>>>(X, Xn);
  cvt_both_kernel<<<5120, 256, 0, stream>>>(W_in, W_out, Wi);
  gemm_p_kernel<<<dim3(32, 32), 256, 0, stream>>>(Xn, Wi, b_in, P, 4096, 4096, 1024);
  transv_kernel<<<dim3(32, 32), 256, 0, stream>>>(P, Vt);
  norms_kernel<<<512, 256, 0, stream>>>(P, nrm);
  attn_kernel<<<dim3(16, 32), 512, 0, stream>>>(P, Vt, nrm, O);
  gemm_out_kernel<<<dim3(8, 32), 256, 0, stream>>>(O, Wo, b_out, X, out, 4096, 1024, 1024);
}

// Round 8
// 154.674 us; speedup vs baseline: 1.1540x; 1.1011x over previous
//
#include <hip/hip_runtime.h>

#define SEQ 2048
#define D_MODEL 1024
#define NTOK 4096
#define PROW 4096
#define DH 64
#define LN_EPS 1e-5f
#define SHEP_EPS 1e-4f

typedef __attribute__((ext_vector_type(8))) short bf16x8;
typedef __attribute__((ext_vector_type(4))) short s16x4;
typedef __attribute__((ext_vector_type(4))) float f32x4;

__device__ __forceinline__ unsigned short f2bf(float f) {
  union { float f; unsigned u; } v; v.f = f;
  unsigned r = v.u + 0x7fffu + ((v.u >> 16) & 1u);
  return (unsigned short)(r >> 16);
}
__device__ __forceinline__ float bf2f(unsigned short s) {
  union { unsigned u; float f; } v; v.u = ((unsigned)s) << 16;
  return v.f;
}
__device__ __forceinline__ void gload16(const void* g, void* l) {
  __builtin_amdgcn_global_load_lds(
      (const __attribute__((address_space(1))) unsigned int*)g,
      (__attribute__((address_space(3))) unsigned int*)l, 16, 0, 0);
}
__device__ __forceinline__ void gload4(const void* g, void* l) {
  __builtin_amdgcn_global_load_lds(
      (const __attribute__((address_space(1))) unsigned int*)g,
      (__attribute__((address_space(3))) unsigned int*)l, 4, 0, 0);
}
__device__ __forceinline__ unsigned cvt_pk_bf16(float lo, float hi) {
  unsigned r;
  asm("v_cvt_pk_bf16_f32 %0, %1, %2" : "=v"(r) : "v"(lo), "v"(hi));
  return r;
}
#define MFMA16(a, b, c) __builtin_amdgcn_mfma_f32_16x16x32_bf16(a, b, c, 0, 0, 0)

// XCD-aware bijective block swizzle (T1): valid since nwg % 8 == 0.
__device__ __forceinline__ int xcd_swizzle(int linear, int nwg) {
  int cpx = nwg >> 3;
  return (linear & 7) * cpx + (linear >> 3);
}

// ---------------- LayerNorm: f32 row -> bf16 row ----------------
__global__ __launch_bounds__(256) void ln_kernel(const float* __restrict__ X,
                                                 unsigned short* __restrict__ Xn) {
  int row = blockIdx.x, tid = threadIdx.x;
  const float4* xr = (const float4*)(X + (size_t)row * D_MODEL);
  float4 v = xr[tid];
  float s = v.x + v.y + v.z + v.w;
  float s2 = v.x * v.x + v.y * v.y + v.z * v.z + v.w * v.w;
#pragma unroll
  for (int off = 32; off > 0; off >>= 1) {
    s += __shfl_down(s, off);
    s2 += __shfl_down(s2, off);
  }
  __shared__ float red[8];
  __shared__ float mb[2];
  int wv = tid >> 6;
  if ((tid & 63) == 0) { red[wv] = s; red[4 + wv] = s2; }
  __syncthreads();
  if (tid == 0) {
    float ts = red[0] + red[1] + red[2] + red[3];
    float t2 = red[4] + red[5] + red[6] + red[7];
    float mu = ts * (1.f / D_MODEL);
    float var = t2 * (1.f / D_MODEL) - mu * mu;
    mb[0] = mu;
    mb[1] = rsqrtf(var + LN_EPS);
  }
  __syncthreads();
  float mu = mb[0], rs = mb[1];
  s16x4 o;
  o[0] = (short)f2bf((v.x - mu) * rs);
  o[1] = (short)f2bf((v.y - mu) * rs);
  o[2] = (short)f2bf((v.z - mu) * rs);
  o[3] = (short)f2bf((v.w - mu) * rs);
  ((s16x4*)(Xn + (size_t)row * D_MODEL))[tid] = o;
}

// ---------------- fused f32 -> bf16 convert (W_in then W_out, contiguous dest) ----------------
__global__ __launch_bounds__(256) void cvt_both_kernel(const float* __restrict__ Win,
                                                       const float* __restrict__ Wout,
                                                       unsigned short* __restrict__ dst) {
  const int N1 = (4096 * 1024) / 4;       // W_in float4 count
  const int N2 = (1024 * 1024) / 4;       // W_out float4 count
  int i = blockIdx.x * 256 + threadIdx.x;
  if (i >= N1 + N2) return;
  float4 v = (i < N1) ? ((const float4*)Win)[i] : ((const float4*)Wout)[i - N1];
  s16x4 o;
  o[0] = (short)f2bf(v.x);
  o[1] = (short)f2bf(v.y);
  o[2] = (short)f2bf(v.z);
  o[3] = (short)f2bf(v.w);
  ((s16x4*)dst)[i] = o;
}

// ---------------- GEMM (NT, bf16 in, bf16 out + bias) : P = Xn*Wi^T + b ----------------
// BK=64 K-steps; LDS tiles [128][64] bf16 = 128-B rows with 16-B-group XOR
// swizzle g^=(row&7): conflict-free ds_read_b128 (lanes lr=0..7 hit 8 distinct
// 16B slots = all 32 banks; lr 8..15 alias 2-way = free). Swizzle applied on
// the pre-swizzled global source (gload_lds writes linearly) + on frag reads.
__global__ __launch_bounds__(256) void gemm_p_kernel(
    const unsigned short* __restrict__ A, const unsigned short* __restrict__ B,
    const float* __restrict__ bias, unsigned short* __restrict__ C,
    int M, int N, int K) {
  __shared__ __align__(16) unsigned short sA[128 * 64];
  __shared__ __align__(16) unsigned short sB[128 * 64];
  int tid = threadIdx.x;
  int nwg = gridDim.x * gridDim.y;
  int swz = xcd_swizzle(blockIdx.y * gridDim.x + blockIdx.x, nwg);
  int m0 = (swz / gridDim.x) * 128, n0 = (swz % gridDim.x) * 128;
  int wv = tid >> 6, lane = tid & 63;
  int wr = wv >> 1, wc = wv & 1;
  int lr = lane & 15, lq = lane >> 4;
  f32x4 acc[4][4] = {};
  for (int k0 = 0; k0 < K; k0 += 64) {
#pragma unroll
    for (int it = 0; it < 4; it++) {
      int c = tid + it * 256;
      int row = c >> 3;
      int col = ((c & 7) ^ (row & 7)) * 8;  // pre-swizzled source chunk
      gload16(A + (size_t)(m0 + row) * K + k0 + col, (char*)sA + c * 16);
      gload16(B + (size_t)(n0 + row) * K + k0 + col, (char*)sB + c * 16);
    }
    __syncthreads();
#pragma unroll
    for (int ks = 0; ks < 2; ks++) {
      bf16x8 af[4], bfr[4];
#pragma unroll
      for (int m = 0; m < 4; m++) {
        int row = wr * 64 + m * 16 + lr;
        af[m] = *(const bf16x8*)((const char*)sA + row * 128 +
                                 (((ks * 4 + lq) ^ (lr & 7)) * 16));
      }
#pragma unroll
      for (int n = 0; n < 4; n++) {
        int row = wc * 64 + n * 16 + lr;
        bfr[n] = *(const bf16x8*)((const char*)sB + row * 128 +
                                  (((ks * 4 + lq) ^ (lr & 7)) * 16));
      }
#pragma unroll
      for (int m = 0; m < 4; m++)
#pragma unroll
        for (int n = 0; n < 4; n++)
          acc[m][n] = MFMA16(af[m], bfr[n], acc[m][n]);
    }
    __syncthreads();
  }
#pragma unroll
  for (int m = 0; m < 4; m++) {
    int row = m0 + wr * 64 + m * 16 + lq * 4;
#pragma unroll
    for (int n = 0; n < 4; n++) {
      int col = n0 + wc * 64 + n * 16 + lr;
      float bv = bias[col];
#pragma unroll
      for (int r = 0; r < 4; r++)
        C[(size_t)(row + r) * N + col] = f2bf(acc[m][n][r] + bv);
    }
  }
}

// ---------------- GEMM (NT) + residual + bias, f32 out : out = X + O*Wo^T + b ----------------
__global__ __launch_bounds__(256) void gemm_out_kernel(
    const unsigned short* __restrict__ A, const unsigned short* __restrict__ B,
    const float* __restrict__ bias, const float* __restrict__ Xres,
    float* __restrict__ Out, int M, int N, int K) {
  __shared__ __align__(16) unsigned short sA[128 * 64];
  __shared__ __align__(16) unsigned short sB[128 * 64];
  int tid = threadIdx.x;
  int nwg = gridDim.x * gridDim.y;
  int swz = xcd_swizzle(blockIdx.y * gridDim.x + blockIdx.x, nwg);
  int m0 = (swz / gridDim.x) * 128, n0 = (swz % gridDim.x) * 128;
  int wv = tid >> 6, lane = tid & 63;
  int wr = wv >> 1, wc = wv & 1;
  int lr = lane & 15, lq = lane >> 4;
  f32x4 acc[4][4] = {};
  for (int k0 = 0; k0 < K; k0 += 64) {
#pragma unroll
    for (int it = 0; it < 4; it++) {
      int c = tid + it * 256;
      int row = c >> 3;
      int col = ((c & 7) ^ (row & 7)) * 8;
      gload16(A + (size_t)(m0 + row) * K + k0 + col, (char*)sA + c * 16);
      gload16(B + (size_t)(n0 + row) * K + k0 + col, (char*)sB + c * 16);
    }
    __syncthreads();
#pragma unroll
    for (int ks = 0; ks < 2; ks++) {
      bf16x8 af[4], bfr[4];
#pragma unroll
      for (int m = 0; m < 4; m++) {
        int row = wr * 64 + m * 16 + lr;
        af[m] = *(const bf16x8*)((const char*)sA + row * 128 +
                                 (((ks * 4 + lq) ^ (lr & 7)) * 16));
      }
#pragma unroll
      for (int n = 0; n < 4; n++) {
        int row = wc * 64 + n * 16 + lr;
        bfr[n] = *(const bf16x8*)((const char*)sB + row * 128 +
                                  (((ks * 4 + lq) ^ (lr & 7)) * 16));
      }
#pragma unroll
      for (int m = 0; m < 4; m++)
#pragma unroll
        for (int n = 0; n < 4; n++)
          acc[m][n] = MFMA16(af[m], bfr[n], acc[m][n]);
    }
    __syncthreads();
  }
#pragma unroll
  for (int m = 0; m < 4; m++) {
    int row = m0 + wr * 64 + m * 16 + lq * 4;
#pragma unroll
    for (int n = 0; n < 4; n++) {
      int col = n0 + wc * 64 + n * 16 + lr;
      float bv = bias[col];
#pragma unroll
      for (int r = 0; r < 4; r++) {
        size_t idx = (size_t)(row + r) * N + col;
        Out[idx] = Xres[idx] + acc[m][n][r] + bv;
      }
    }
  }
}

// ---------------- V transpose: P's V slice [t][c] -> Vt[bh][c][t] ----------------
__global__ __launch_bounds__(256) void transv_kernel(const unsigned short* __restrict__ P,
                                                     unsigned short* __restrict__ Vt) {
  int kt = blockIdx.x;  // t-tile of 64
  int bh = blockIdx.y;
  int b = bh >> 4, h = bh & 15;
  __shared__ unsigned short sT[64][72];  // [c][k]
  int tid = threadIdx.x;
  const unsigned short* vbase = P + ((size_t)(b * SEQ + kt * 64)) * PROW + h * 256 + 128;
#pragma unroll
  for (int it = 0; it < 2; it++) {
    int c = tid + it * 256;
    int k = c >> 3, c0 = (c & 7) * 8;
    uint4 u = *(const uint4*)(vbase + (size_t)k * PROW + c0);
    unsigned e[4] = {u.x, u.y, u.z, u.w};
#pragma unroll
    for (int j = 0; j < 4; j++) {
      sT[c0 + 2 * j][k] = (unsigned short)(e[j] & 0xffffu);
      sT[c0 + 2 * j + 1][k] = (unsigned short)(e[j] >> 16);
    }
  }
  __syncthreads();
  unsigned short* obase = Vt + (size_t)bh * 64 * SEQ + kt * 64;
#pragma unroll
  for (int it = 0; it < 2; it++) {
    int cc = tid + it * 256;
    int crow = cc >> 3, k0 = (cc & 7) * 8;
    uint4 o;
    unsigned short e[8];
#pragma unroll
    for (int j = 0; j < 8; j++) e[j] = sT[crow][k0 + j];
    o.x = (unsigned)e[0] | ((unsigned)e[1] << 16);
    o.y = (unsigned)e[2] | ((unsigned)e[3] << 16);
    o.z = (unsigned)e[4] | ((unsigned)e[5] << 16);
    o.w = (unsigned)e[6] | ((unsigned)e[7] << 16);
    *(uint4*)(obase + (size_t)crow * SEQ + k0) = o;
  }
}

// ---------------- row norms of Q and K slices (from bf16 P) ----------------
__global__ __launch_bounds__(256) void norms_kernel(const unsigned short* __restrict__ P,
                                                    float* __restrict__ nrm) {
  int id = blockIdx.x * 256 + threadIdx.x;  // 32*2*2048
  int bh = id >> 12;
  int which = (id >> 11) & 1;
  int t = id & 2047;
  int b = bh >> 4, h = bh & 15;
  const unsigned short* p = P + ((size_t)(b * SEQ + t)) * PROW + h * 256 + which * 64;
  const uint4* pv = (const uint4*)p;
  float acc = 0.f;
#pragma unroll
  for (int i = 0; i < 8; i++) {
    uint4 u = pv[i];
    unsigned arr[4] = {u.x, u.y, u.z, u.w};
#pragma unroll
    for (int j = 0; j < 4; j++) {
      float lo = __uint_as_float(arr[j] << 16);
      float hi = __uint_as_float(arr[j] & 0xffff0000u);
      acc += lo * lo + hi * hi;
    }
  }
  nrm[(size_t)(bh * 2 + which) * SEQ + t] = acc;
}

// ---------------- Shepard attention (8 waves x 16 q-rows) -- r2-proven + setprio ----------------
__global__ __launch_bounds__(512) void attn_kernel(
    const unsigned short* __restrict__ P, const unsigned short* __restrict__ Vt,
    const float* __restrict__ nrm, unsigned short* __restrict__ O) {
  int qt = blockIdx.x, bh = blockIdx.y;
  int b = bh >> 4, h = bh & 15;
  int tid = threadIdx.x;
  int w = tid >> 6, lane = tid & 63;
  int lr = lane & 15, lq = lane >> 4;

  __shared__ __align__(16) unsigned short sQ[128 * 64];
  __shared__ __align__(16) unsigned short sK[2][64 * 64];
  __shared__ __align__(16) unsigned short sV[2][64 * 64];
  __shared__ __align__(16) unsigned short sW[128 * 64];  // wave-private 16-row slabs
  __shared__ __align__(16) float sK2[2][64];
  __shared__ __align__(16) float sDen[8][16];

  const unsigned short* qbase = P + ((size_t)(b * SEQ + qt * 128)) * PROW + h * 256;
  const unsigned short* kbase = P + ((size_t)(b * SEQ)) * PROW + h * 256 + 64;
  const unsigned short* vtb = Vt + (size_t)bh * 64 * SEQ;
  const float* k2base = nrm + (size_t)(bh * 2 + 1) * SEQ;

  // staging source addresses (pre-swizzled column)
  int srow = tid >> 3;
  int scol = ((tid & 7) ^ (srow & 7)) * 8;
  const unsigned short* kSrc = kbase + (size_t)srow * PROW + scol;
  const unsigned short* vSrc = vtb + (size_t)srow * SEQ + scol;

  // ---- prologue: stage Q, K/V tile 0, k2 tile 0
#pragma unroll
  for (int it = 0; it < 2; it++) {
    int c = tid + it * 512;
    int row = c >> 3;
    int col = ((c & 7) ^ (row & 7)) * 8;
    gload16(qbase + (size_t)row * PROW + col, (char*)sQ + c * 16);
  }
  gload16(kSrc, (char*)&sK[0][0] + tid * 16);
  gload16(vSrc, (char*)&sV[0][0] + tid * 16);
  if (w == 0) gload4(k2base + lane, (char*)&sK2[0][0] + lane * 4);
  float q2 = nrm[(size_t)(bh * 2) * SEQ + qt * 128 + 16 * w + lr];
  __syncthreads();

  // hoist Q fragments (B-operand of S^T = K.Q^T); sQ not touched again
  int qrow = 16 * w + lr;
  bf16x8 qf[2];
#pragma unroll
  for (int ks = 0; ks < 2; ks++)
    qf[ks] = *(const bf16x8*)((const char*)sQ + qrow * 128 +
                              ((ks * 64 + lq * 16) ^ ((lr & 7) << 4)));

  f32x4 num[4] = {};
  float den = 0.f;
  char* wrow = (char*)sW + qrow * 128;

  for (int kt = 0; kt < SEQ / 64; kt++) {
    int cur = kt & 1, nxt = cur ^ 1;
    // prefetch next K/V tile (drained by the barrier at the END of this phase)
    if (kt < SEQ / 64 - 1) {
      gload16(kSrc + (size_t)(kt + 1) * 64 * PROW, (char*)&sK[nxt][0] + tid * 16);
      gload16(vSrc + (size_t)(kt + 1) * 64, (char*)&sV[nxt][0] + tid * 16);
      if (w == 0) gload4(k2base + (kt + 1) * 64 + lane, (char*)&sK2[nxt][0] + lane * 4);
    }

    // S^T[k][q] = K . Q^T
    f32x4 st[4] = {};
    __builtin_amdgcn_s_setprio(1);
#pragma unroll
    for (int fk = 0; fk < 4; fk++) {
      int row = 16 * fk + lr;
      const char* krow = (const char*)&sK[cur][0] + row * 128;
      bf16x8 kf0 = *(const bf16x8*)(krow + ((lq * 16) ^ ((row & 7) << 4)));
      bf16x8 kf1 = *(const bf16x8*)(krow + ((64 + lq * 16) ^ ((row & 7) << 4)));
      st[fk] = MFMA16(kf0, qf[0], st[fk]);
      st[fk] = MFMA16(kf1, qf[1], st[fk]);
    }
    __builtin_amdgcn_s_setprio(0);

    // weights: w = rcp(max(q2+k2-2*st, 1e-8)); pack bf16 pairs; stash in sW
#pragma unroll
    for (int fk = 0; fk < 4; fk++) {
      f32x4 k2v = *(const f32x4*)&sK2[cur][16 * fk + 4 * lq];
      float w0 = __builtin_amdgcn_rcpf(fmaxf(fmaf(-2.f, st[fk][0], q2 + k2v[0]), 1e-8f));
      float w1 = __builtin_amdgcn_rcpf(fmaxf(fmaf(-2.f, st[fk][1], q2 + k2v[1]), 1e-8f));
      float w2 = __builtin_amdgcn_rcpf(fmaxf(fmaf(-2.f, st[fk][2], q2 + k2v[2]), 1e-8f));
      float w3 = __builtin_amdgcn_rcpf(fmaxf(fmaf(-2.f, st[fk][3], q2 + k2v[3]), 1e-8f));
      den += (w0 + w1) + (w2 + w3);
      uint2 pp;
      pp.x = cvt_pk_bf16(w0, w1);
      pp.y = cvt_pk_bf16(w2, w3);
      *(uint2*)(wrow + ((32 * fk + 8 * lq) ^ ((lr & 7) << 4))) = pp;
    }

    // PV: num[c] += W . V^T  (sW rows are this wave's own -> no barrier needed)
    __builtin_amdgcn_s_setprio(1);
#pragma unroll
    for (int ks = 0; ks < 2; ks++) {
      bf16x8 aw = *(const bf16x8*)(wrow + ((64 * ks + 16 * lq) ^ ((lr & 7) << 4)));
#pragma unroll
      for (int fn = 0; fn < 4; fn++) {
        int row = 16 * fn + lr;
        bf16x8 bv = *(const bf16x8*)((const char*)&sV[cur][0] + row * 128 +
                                     ((64 * ks + 16 * lq) ^ ((row & 7) << 4)));
        num[fn] = MFMA16(aw, bv, num[fn]);
      }
    }
    __builtin_amdgcn_s_setprio(0);
    __syncthreads();  // implicit vmcnt(0)+lgkmcnt(0): next tile staged & all reads done
  }

  // den: full sum over k lives split across the 4 lq-groups
  den += __shfl_xor(den, 16);
  den += __shfl_xor(den, 32);
  if (lq == 0) sDen[w][lr] = den;
  __syncthreads();
  f32x4 dv = *(const f32x4*)&sDen[w][4 * lq];
  f32x4 rdv;
#pragma unroll
  for (int r = 0; r < 4; r++) rdv[r] = __builtin_amdgcn_rcpf(dv[r] + SHEP_EPS);

  // epilogue: gate with G and store bf16 O
  const unsigned short* gbase = qbase + 192;
#pragma unroll
  for (int fn = 0; fn < 4; fn++) {
    int c = 16 * fn + lr;
#pragma unroll
    for (int r = 0; r < 4; r++) {
      int ql = 16 * w + 4 * lq + r;
      float g = bf2f(gbase[(size_t)ql * PROW + c]);
      float a = num[fn][r] * rdv[r];
      O[((size_t)(b * SEQ + qt * 128 + ql)) * D_MODEL + h * DH + c] = f2bf(g * a);
    }
  }
}

extern "C" void kernel_launch(void* const* d_in, const int* in_sizes, int n_in,
                              void* d_out, int out_size, void* d_ws, size_t ws_size,
                              hipStream_t stream) {
  const float* X = (const float*)d_in[0];
  const float* W_in = (const float*)d_in[1];
  const float* b_in = (const float*)d_in[2];
  const float* W_out = (const float*)d_in[3];
  const float* b_out = (const float*)d_in[4];
  float* out = (float*)d_out;

  // ws layout:
  //   [0,8MB):    Xn (bf16)        -> reused as O (gated attn output, bf16)
  //   [8,16MB):   Wi bf16          -> reused as Vt (transposed V, bf16)
  //   [16,18MB):  Wo bf16 (contiguous after Wi -> fused cvt)
  //   [18,50MB):  P = QKVG (bf16, [4096][4096])
  //   [50MB,+512K): q2/k2 norms (f32)
  char* ws = (char*)d_ws;
  unsigned short* Xn = (unsigned short*)(ws);
  unsigned short* O = (unsigned short*)(ws);
  unsigned short* Wi = (unsigned short*)(ws + ((size_t)8 << 20));
  unsigned short* Vt = (unsigned short*)(ws + ((size_t)8 << 20));
  unsigned short* Wo = (unsigned short*)(ws + ((size_t)16 << 20));
  unsigned short* P = (unsigned short*)(ws + ((size_t)18 << 20));
  float* nrm = (float*)(ws + ((size_t)50 << 20));

  ln_kernel<<<NTOK, 256, 0, stream>>>(X, Xn);
  cvt_both_kernel<<<5120, 256, 0, stream>>>(W_in, W_out, Wi);
  gemm_p_kernel<<<dim3(32, 32), 256, 0, stream>>>(Xn, Wi, b_in, P, 4096, 4096, 1024);
  transv_kernel<<<dim3(32, 32), 256, 0, stream>>>(P, Vt);
  norms_kernel<<<512, 256, 0, stream>>>(P, nrm);
  attn_kernel<<<dim3(16, 32), 512, 0, stream>>>(P, Vt, nrm, O);
  gemm_out_kernel<<<dim3(8, 32), 256, 0, stream>>>(O, Wo, b_out, X, out, 4096, 1024, 1024);
}

// Round 9
// 153.889 us; speedup vs baseline: 1.1599x; 1.0051x over previous
//
#include <hip/hip_runtime.h>

#define SEQ 2048
#define D_MODEL 1024
#define NTOK 4096
#define PROW 4096
#define DH 64
#define LN_EPS 1e-5f
#define SHEP_EPS 1e-4f

typedef __attribute__((ext_vector_type(8))) short bf16x8;
typedef __attribute__((ext_vector_type(4))) short s16x4;
typedef __attribute__((ext_vector_type(4))) float f32x4;

__device__ __forceinline__ unsigned short f2bf(float f) {
  union { float f; unsigned u; } v; v.f = f;
  unsigned r = v.u + 0x7fffu + ((v.u >> 16) & 1u);
  return (unsigned short)(r >> 16);
}
__device__ __forceinline__ float bf2f(unsigned short s) {
  union { unsigned u; float f; } v; v.u = ((unsigned)s) << 16;
  return v.f;
}
__device__ __forceinline__ void gload16(const void* g, void* l) {
  __builtin_amdgcn_global_load_lds(
      (const __attribute__((address_space(1))) unsigned int*)g,
      (__attribute__((address_space(3))) unsigned int*)l, 16, 0, 0);
}
__device__ __forceinline__ void gload4(const void* g, void* l) {
  __builtin_amdgcn_global_load_lds(
      (const __attribute__((address_space(1))) unsigned int*)g,
      (__attribute__((address_space(3))) unsigned int*)l, 4, 0, 0);
}
__device__ __forceinline__ unsigned cvt_pk_bf16(float lo, float hi) {
  unsigned r;
  asm("v_cvt_pk_bf16_f32 %0, %1, %2" : "=v"(r) : "v"(lo), "v"(hi));
  return r;
}
#define MFMA16(a, b, c) __builtin_amdgcn_mfma_f32_16x16x32_bf16(a, b, c, 0, 0, 0)

// XCD-aware bijective block swizzle (T1): valid since nwg % 8 == 0.
__device__ __forceinline__ int xcd_swizzle(int linear, int nwg) {
  int cpx = nwg >> 3;
  return (linear & 7) * cpx + (linear >> 3);
}

// ---------------- LayerNorm: f32 row -> bf16 row ----------------
__global__ __launch_bounds__(256) void ln_kernel(const float* __restrict__ X,
                                                 unsigned short* __restrict__ Xn) {
  int row = blockIdx.x, tid = threadIdx.x;
  const float4* xr = (const float4*)(X + (size_t)row * D_MODEL);
  float4 v = xr[tid];
  float s = v.x + v.y + v.z + v.w;
  float s2 = v.x * v.x + v.y * v.y + v.z * v.z + v.w * v.w;
#pragma unroll
  for (int off = 32; off > 0; off >>= 1) {
    s += __shfl_down(s, off);
    s2 += __shfl_down(s2, off);
  }
  __shared__ float red[8];
  __shared__ float mb[2];
  int wv = tid >> 6;
  if ((tid & 63) == 0) { red[wv] = s; red[4 + wv] = s2; }
  __syncthreads();
  if (tid == 0) {
    float ts = red[0] + red[1] + red[2] + red[3];
    float t2 = red[4] + red[5] + red[6] + red[7];
    float mu = ts * (1.f / D_MODEL);
    float var = t2 * (1.f / D_MODEL) - mu * mu;
    mb[0] = mu;
    mb[1] = rsqrtf(var + LN_EPS);
  }
  __syncthreads();
  float mu = mb[0], rs = mb[1];
  s16x4 o;
  o[0] = (short)f2bf((v.x - mu) * rs);
  o[1] = (short)f2bf((v.y - mu) * rs);
  o[2] = (short)f2bf((v.z - mu) * rs);
  o[3] = (short)f2bf((v.w - mu) * rs);
  ((s16x4*)(Xn + (size_t)row * D_MODEL))[tid] = o;
}

// ---------------- fused f32 -> bf16 convert (W_in then W_out, contiguous dest) ----------------
__global__ __launch_bounds__(256) void cvt_both_kernel(const float* __restrict__ Win,
                                                       const float* __restrict__ Wout,
                                                       unsigned short* __restrict__ dst) {
  const int N1 = (4096 * 1024) / 4;       // W_in float4 count
  const int N2 = (1024 * 1024) / 4;       // W_out float4 count
  int i = blockIdx.x * 256 + threadIdx.x;
  if (i >= N1 + N2) return;
  float4 v = (i < N1) ? ((const float4*)Win)[i] : ((const float4*)Wout)[i - N1];
  s16x4 o;
  o[0] = (short)f2bf(v.x);
  o[1] = (short)f2bf(v.y);
  o[2] = (short)f2bf(v.z);
  o[3] = (short)f2bf(v.w);
  ((s16x4*)dst)[i] = o;
}

// ---------------- GEMM (NT, bf16 in, bf16 out + bias) : P = Xn*Wi^T + b ----------------
// BK=64 K-steps; LDS tiles [128][64] bf16 = 128-B rows with 16-B-group XOR
// swizzle g^=(row&7): conflict-free ds_read_b128. Swizzle applied on the
// pre-swizzled global source (gload_lds writes linearly) + on frag reads.
__global__ __launch_bounds__(256) void gemm_p_kernel(
    const unsigned short* __restrict__ A, const unsigned short* __restrict__ B,
    const float* __restrict__ bias, unsigned short* __restrict__ C,
    int M, int N, int K) {
  __shared__ __align__(16) unsigned short sA[128 * 64];
  __shared__ __align__(16) unsigned short sB[128 * 64];
  int tid = threadIdx.x;
  int nwg = gridDim.x * gridDim.y;
  int swz = xcd_swizzle(blockIdx.y * gridDim.x + blockIdx.x, nwg);
  int m0 = (swz / gridDim.x) * 128, n0 = (swz % gridDim.x) * 128;
  int wv = tid >> 6, lane = tid & 63;
  int wr = wv >> 1, wc = wv & 1;
  int lr = lane & 15, lq = lane >> 4;
  f32x4 acc[4][4] = {};
  for (int k0 = 0; k0 < K; k0 += 64) {
#pragma unroll
    for (int it = 0; it < 4; it++) {
      int c = tid + it * 256;
      int row = c >> 3;
      int col = ((c & 7) ^ (row & 7)) * 8;  // pre-swizzled source chunk
      gload16(A + (size_t)(m0 + row) * K + k0 + col, (char*)sA + c * 16);
      gload16(B + (size_t)(n0 + row) * K + k0 + col, (char*)sB + c * 16);
    }
    __syncthreads();
#pragma unroll
    for (int ks = 0; ks < 2; ks++) {
      bf16x8 af[4], bfr[4];
#pragma unroll
      for (int m = 0; m < 4; m++) {
        int row = wr * 64 + m * 16 + lr;
        af[m] = *(const bf16x8*)((const char*)sA + row * 128 +
                                 (((ks * 4 + lq) ^ (lr & 7)) * 16));
      }
#pragma unroll
      for (int n = 0; n < 4; n++) {
        int row = wc * 64 + n * 16 + lr;
        bfr[n] = *(const bf16x8*)((const char*)sB + row * 128 +
                                  (((ks * 4 + lq) ^ (lr & 7)) * 16));
      }
#pragma unroll
      for (int m = 0; m < 4; m++)
#pragma unroll
        for (int n = 0; n < 4; n++)
          acc[m][n] = MFMA16(af[m], bfr[n], acc[m][n]);
    }
    __syncthreads();
  }
#pragma unroll
  for (int m = 0; m < 4; m++) {
    int row = m0 + wr * 64 + m * 16 + lq * 4;
#pragma unroll
    for (int n = 0; n < 4; n++) {
      int col = n0 + wc * 64 + n * 16 + lr;
      float bv = bias[col];
#pragma unroll
      for (int r = 0; r < 4; r++)
        C[(size_t)(row + r) * N + col] = f2bf(acc[m][n][r] + bv);
    }
  }
}

// ---------------- GEMM (NT) + residual + bias, f32 out : out = X + O*Wo^T + b ----------------
__global__ __launch_bounds__(256) void gemm_out_kernel(
    const unsigned short* __restrict__ A, const unsigned short* __restrict__ B,
    const float* __restrict__ bias, const float* __restrict__ Xres,
    float* __restrict__ Out, int M, int N, int K) {
  __shared__ __align__(16) unsigned short sA[128 * 64];
  __shared__ __align__(16) unsigned short sB[128 * 64];
  int tid = threadIdx.x;
  int nwg = gridDim.x * gridDim.y;
  int swz = xcd_swizzle(blockIdx.y * gridDim.x + blockIdx.x, nwg);
  int m0 = (swz / gridDim.x) * 128, n0 = (swz % gridDim.x) * 128;
  int wv = tid >> 6, lane = tid & 63;
  int wr = wv >> 1, wc = wv & 1;
  int lr = lane & 15, lq = lane >> 4;
  f32x4 acc[4][4] = {};
  for (int k0 = 0; k0 < K; k0 += 64) {
#pragma unroll
    for (int it = 0; it < 4; it++) {
      int c = tid + it * 256;
      int row = c >> 3;
      int col = ((c & 7) ^ (row & 7)) * 8;
      gload16(A + (size_t)(m0 + row) * K + k0 + col, (char*)sA + c * 16);
      gload16(B + (size_t)(n0 + row) * K + k0 + col, (char*)sB + c * 16);
    }
    __syncthreads();
#pragma unroll
    for (int ks = 0; ks < 2; ks++) {
      bf16x8 af[4], bfr[4];
#pragma unroll
      for (int m = 0; m < 4; m++) {
        int row = wr * 64 + m * 16 + lr;
        af[m] = *(const bf16x8*)((const char*)sA + row * 128 +
                                 (((ks * 4 + lq) ^ (lr & 7)) * 16));
      }
#pragma unroll
      for (int n = 0; n < 4; n++) {
        int row = wc * 64 + n * 16 + lr;
        bfr[n] = *(const bf16x8*)((const char*)sB + row * 128 +
                                  (((ks * 4 + lq) ^ (lr & 7)) * 16));
      }
#pragma unroll
      for (int m = 0; m < 4; m++)
#pragma unroll
        for (int n = 0; n < 4; n++)
          acc[m][n] = MFMA16(af[m], bfr[n], acc[m][n]);
    }
    __syncthreads();
  }
#pragma unroll
  for (int m = 0; m < 4; m++) {
    int row = m0 + wr * 64 + m * 16 + lq * 4;
#pragma unroll
    for (int n = 0; n < 4; n++) {
      int col = n0 + wc * 64 + n * 16 + lr;
      float bv = bias[col];
#pragma unroll
      for (int r = 0; r < 4; r++) {
        size_t idx = (size_t)(row + r) * N + col;
        Out[idx] = Xres[idx] + acc[m][n][r] + bv;
      }
    }
  }
}

// ---------------- V transpose: P's V slice [t][c] -> Vt[bh][c][t] ----------------
__global__ __launch_bounds__(256) void transv_kernel(const unsigned short* __restrict__ P,
                                                     unsigned short* __restrict__ Vt) {
  int kt = blockIdx.x;  // t-tile of 64
  int bh = blockIdx.y;
  int b = bh >> 4, h = bh & 15;
  __shared__ unsigned short sT[64][72];  // [c][k]
  int tid = threadIdx.x;
  const unsigned short* vbase = P + ((size_t)(b * SEQ + kt * 64)) * PROW + h * 256 + 128;
#pragma unroll
  for (int it = 0; it < 2; it++) {
    int c = tid + it * 256;
    int k = c >> 3, c0 = (c & 7) * 8;
    uint4 u = *(const uint4*)(vbase + (size_t)k * PROW + c0);
    unsigned e[4] = {u.x, u.y, u.z, u.w};
#pragma unroll
    for (int j = 0; j < 4; j++) {
      sT[c0 + 2 * j][k] = (unsigned short)(e[j] & 0xffffu);
      sT[c0 + 2 * j + 1][k] = (unsigned short)(e[j] >> 16);
    }
  }
  __syncthreads();
  unsigned short* obase = Vt + (size_t)bh * 64 * SEQ + kt * 64;
#pragma unroll
  for (int it = 0; it < 2; it++) {
    int cc = tid + it * 256;
    int crow = cc >> 3, k0 = (cc & 7) * 8;
    uint4 o;
    unsigned short e[8];
#pragma unroll
    for (int j = 0; j < 8; j++) e[j] = sT[crow][k0 + j];
    o.x = (unsigned)e[0] | ((unsigned)e[1] << 16);
    o.y = (unsigned)e[2] | ((unsigned)e[3] << 16);
    o.z = (unsigned)e[4] | ((unsigned)e[5] << 16);
    o.w = (unsigned)e[6] | ((unsigned)e[7] << 16);
    *(uint4*)(obase + (size_t)crow * SEQ + k0) = o;
  }
}

// ---------------- row norms of Q and K slices (from bf16 P) ----------------
__global__ __launch_bounds__(256) void norms_kernel(const unsigned short* __restrict__ P,
                                                    float* __restrict__ nrm) {
  int id = blockIdx.x * 256 + threadIdx.x;  // 32*2*2048
  int bh = id >> 12;
  int which = (id >> 11) & 1;
  int t = id & 2047;
  int b = bh >> 4, h = bh & 15;
  const unsigned short* p = P + ((size_t)(b * SEQ + t)) * PROW + h * 256 + which * 64;
  const uint4* pv = (const uint4*)p;
  float acc = 0.f;
#pragma unroll
  for (int i = 0; i < 8; i++) {
    uint4 u = pv[i];
    unsigned arr[4] = {u.x, u.y, u.z, u.w};
#pragma unroll
    for (int j = 0; j < 4; j++) {
      float lo = __uint_as_float(arr[j] << 16);
      float hi = __uint_as_float(arr[j] & 0xffff0000u);
      acc += lo * lo + hi * hi;
    }
  }
  nrm[(size_t)(bh * 2 + which) * SEQ + t] = acc;
}

// ---------------- Shepard attention (4 waves x 32 q-rows, 128 q-rows/block) ----------------
// r6's PASSED compute/den path (shfl+sDen; NO dacc) + r4's depth-2 counted-
// vmcnt pipeline (r4/r5/r6 bisect showed dacc -- not the pipeline -- was the
// r4 bug). Schedule per iter:
//   wait vmcnt(4|5) [tile t's loads done; t+1's stay in flight] -> barrier ->
//   compute tile t -> barrier -> stage tile t+2 into t's buffer.
// Counts: stage_kv = 4 gload16/thread + (wave0 only) 1 gload4 -> 4|5 per wave.
// Prologue __syncthreads fully drains Q+tiles0,1, so counts start at 0.
// vmcnt-wait BEFORE each barrier publishes all waves' gload_lds writes.
__global__ __launch_bounds__(256) void attn_kernel(
    const unsigned short* __restrict__ P, const unsigned short* __restrict__ Vt,
    const float* __restrict__ nrm, unsigned short* __restrict__ O) {
  const int NT = SEQ / 64;  // 32
  int qt = blockIdx.x, bh = blockIdx.y;
  int b = bh >> 4, h = bh & 15;
  int tid = threadIdx.x;
  int w = tid >> 6, lane = tid & 63;
  int lr = lane & 15, lq = lane >> 4;

  __shared__ __align__(16) unsigned short sQ[128 * 64];
  __shared__ __align__(16) unsigned short sK[2][64 * 64];
  __shared__ __align__(16) unsigned short sV[2][64 * 64];
  __shared__ __align__(16) unsigned short sW[128 * 64];  // wave-private 32-row slabs
  __shared__ __align__(16) float sK2[2][64];
  __shared__ __align__(16) float sDen[4][2][16];

  const unsigned short* qbase = P + ((size_t)(b * SEQ + qt * 128)) * PROW + h * 256;
  const unsigned short* kbase = P + ((size_t)(b * SEQ)) * PROW + h * 256 + 64;
  const unsigned short* vtb = Vt + (size_t)bh * 64 * SEQ;
  const float* k2base = nrm + (size_t)(bh * 2 + 1) * SEQ;

  auto stage_kv = [&](int t, int buf) {
#pragma unroll
    for (int it = 0; it < 2; it++) {
      int c = tid + it * 256;
      int row = c >> 3;
      int col = ((c & 7) ^ (row & 7)) * 8;
      gload16(kbase + (size_t)(t * 64 + row) * PROW + col, (char*)&sK[buf][0] + c * 16);
      gload16(vtb + (size_t)row * SEQ + t * 64 + col, (char*)&sV[buf][0] + c * 16);
    }
    if (tid < 64) gload4(k2base + t * 64 + tid, (char*)&sK2[buf][0] + tid * 4);
  };

  // ---- prologue: stage Q + tiles 0,1; load q2; ONE full drain
#pragma unroll
  for (int it = 0; it < 4; it++) {
    int c = tid + it * 256;
    int row = c >> 3;
    int col = ((c & 7) ^ (row & 7)) * 8;
    gload16(qbase + (size_t)row * PROW + col, (char*)sQ + c * 16);
  }
  stage_kv(0, 0);
  stage_kv(1, 1);
  float q2f0 = nrm[(size_t)(bh * 2) * SEQ + qt * 128 + 32 * w + lr];
  float q2f1 = nrm[(size_t)(bh * 2) * SEQ + qt * 128 + 32 * w + 16 + lr];
  asm volatile("" ::"v"(q2f0), "v"(q2f1));  // materialize before counted region
  __syncthreads();

  // hoist Q fragments (B-operand of S^T = K.Q^T)
  bf16x8 qf[2][2];
#pragma unroll
  for (int fq = 0; fq < 2; fq++) {
    int row = 32 * w + 16 * fq + lr;
#pragma unroll
    for (int ks = 0; ks < 2; ks++)
      qf[fq][ks] = *(const bf16x8*)((const char*)sQ + row * 128 +
                                    ((ks * 64 + lq * 16) ^ ((row & 7) << 4)));
  }

  f32x4 num[2][4] = {};
  float den[2] = {0.f, 0.f};
  char* wrow0 = (char*)sW + (32 * w + lr) * 128;
  char* wrow1 = (char*)sW + (32 * w + 16 + lr) * 128;

  for (int t = 0; t < NT; t++) {
    int cur = t & 1;
    // tile t's loads done; tile t+1's (4|5 per wave) stay in flight
    if (t == NT - 1)
      asm volatile("s_waitcnt vmcnt(0)" ::: "memory");
    else if (w == 0)
      asm volatile("s_waitcnt vmcnt(5)" ::: "memory");
    else
      asm volatile("s_waitcnt vmcnt(4)" ::: "memory");
    __builtin_amdgcn_sched_barrier(0);
    __builtin_amdgcn_s_barrier();
    __builtin_amdgcn_sched_barrier(0);

    // S^T[k][q] = K . Q^T (K fragments shared across both q-frags)
    f32x4 st[2][4] = {};
    __builtin_amdgcn_s_setprio(1);
#pragma unroll
    for (int fk = 0; fk < 4; fk++) {
      int row = 16 * fk + lr;
      const char* krow = (const char*)&sK[cur][0] + row * 128;
      bf16x8 kf0 = *(const bf16x8*)(krow + ((lq * 16) ^ ((row & 7) << 4)));
      bf16x8 kf1 = *(const bf16x8*)(krow + ((64 + lq * 16) ^ ((row & 7) << 4)));
      st[0][fk] = MFMA16(kf0, qf[0][0], st[0][fk]);
      st[0][fk] = MFMA16(kf1, qf[0][1], st[0][fk]);
      st[1][fk] = MFMA16(kf0, qf[1][0], st[1][fk]);
      st[1][fk] = MFMA16(kf1, qf[1][1], st[1][fk]);
    }
    __builtin_amdgcn_s_setprio(0);

    // weights: w = rcp(max(q2+k2-2*st, 1e-8)); accumulate den; pack bf16 to W slab
#pragma unroll
    for (int fk = 0; fk < 4; fk++) {
      f32x4 k2v = *(const f32x4*)&sK2[cur][16 * fk + 4 * lq];
#pragma unroll
      for (int fq = 0; fq < 2; fq++) {
        float q2 = fq ? q2f1 : q2f0;
        float w0 = __builtin_amdgcn_rcpf(fmaxf(fmaf(-2.f, st[fq][fk][0], q2 + k2v[0]), 1e-8f));
        float w1 = __builtin_amdgcn_rcpf(fmaxf(fmaf(-2.f, st[fq][fk][1], q2 + k2v[1]), 1e-8f));
        float w2 = __builtin_amdgcn_rcpf(fmaxf(fmaf(-2.f, st[fq][fk][2], q2 + k2v[2]), 1e-8f));
        float w3 = __builtin_amdgcn_rcpf(fmaxf(fmaf(-2.f, st[fq][fk][3], q2 + k2v[3]), 1e-8f));
        den[fq] += (w0 + w1) + (w2 + w3);
        uint2 pp;
        pp.x = cvt_pk_bf16(w0, w1);
        pp.y = cvt_pk_bf16(w2, w3);
        char* wr = fq ? wrow1 : wrow0;
        *(uint2*)(wr + ((32 * fk + 8 * lq) ^ ((lr & 7) << 4))) = pp;
      }
    }

    // PV: num += W.V^T (V fragments shared across q-frags)
    __builtin_amdgcn_s_setprio(1);
#pragma unroll
    for (int ks = 0; ks < 2; ks++) {
      bf16x8 aw0 = *(const bf16x8*)(wrow0 + ((64 * ks + 16 * lq) ^ ((lr & 7) << 4)));
      bf16x8 aw1 = *(const bf16x8*)(wrow1 + ((64 * ks + 16 * lq) ^ ((lr & 7) << 4)));
#pragma unroll
      for (int fn = 0; fn < 4; fn++) {
        int row = 16 * fn + lr;
        bf16x8 bv = *(const bf16x8*)((const char*)&sV[cur][0] + row * 128 +
                                     ((64 * ks + 16 * lq) ^ ((row & 7) << 4)));
        num[0][fn] = MFMA16(aw0, bv, num[0][fn]);
        num[1][fn] = MFMA16(aw1, bv, num[1][fn]);
      }
    }
    __builtin_amdgcn_s_setprio(0);

    __builtin_amdgcn_sched_barrier(0);
    __builtin_amdgcn_s_barrier();  // all waves done reading buffer cur
    __builtin_amdgcn_sched_barrier(0);
    if (t + 2 < NT) stage_kv(t + 2, cur);  // overwrite freed buffer
  }

  // den: lanes with same lr hold the 4 lq-partials for q=...+lr; sum them,
  // then LDS round-trip to re-index den by q-local 4lq+r (num's row mapping).
#pragma unroll
  for (int fq = 0; fq < 2; fq++) {
    den[fq] += __shfl_xor(den[fq], 16);
    den[fq] += __shfl_xor(den[fq], 32);
  }
  if (lq == 0) {
    sDen[w][0][lr] = den[0];
    sDen[w][1][lr] = den[1];
  }
  __syncthreads();

  // epilogue: rdv from sDen, gate with G, store bf16 O
  const unsigned short* gbase = qbase + 192;
#pragma unroll
  for (int fq = 0; fq < 2; fq++) {
    f32x4 dv = *(const f32x4*)&sDen[w][fq][4 * lq];
    f32x4 rdv;
#pragma unroll
    for (int r = 0; r < 4; r++)
      rdv[r] = __builtin_amdgcn_rcpf(dv[r] + SHEP_EPS);
#pragma unroll
    for (int fn = 0; fn < 4; fn++) {
      int c = 16 * fn + lr;
#pragma unroll
      for (int r = 0; r < 4; r++) {
        int ql = 32 * w + 16 * fq + 4 * lq + r;
        float g = bf2f(gbase[(size_t)ql * PROW + c]);
        O[((size_t)(b * SEQ + qt * 128 + ql)) * D_MODEL + h * DH + c] =
            f2bf(g * num[fq][fn][r] * rdv[r]);
      }
    }
  }
}

extern "C" void kernel_launch(void* const* d_in, const int* in_sizes, int n_in,
                              void* d_out, int out_size, void* d_ws, size_t ws_size,
                              hipStream_t stream) {
  const float* X = (const float*)d_in[0];
  const float* W_in = (const float*)d_in[1];
  const float* b_in = (const float*)d_in[2];
  const float* W_out = (const float*)d_in[3];
  const float* b_out = (const float*)d_in[4];
  float* out = (float*)d_out;

  // ws layout:
  //   [0,8MB):    Xn (bf16)        -> reused as O (gated attn output, bf16)
  //   [8,16MB):   Wi bf16          -> reused as Vt (transposed V, bf16)
  //   [16,18MB):  Wo bf16 (contiguous after Wi -> fused cvt)
  //   [18,50MB):  P = QKVG (bf16, [4096][4096])
  //   [50MB,+512K): q2/k2 norms (f32)
  char* ws = (char*)d_ws;
  unsigned short* Xn = (unsigned short*)(ws);
  unsigned short* O = (unsigned short*)(ws);
  unsigned short* Wi = (unsigned short*)(ws + ((size_t)8 << 20));
  unsigned short* Vt = (unsigned short*)(ws + ((size_t)8 << 20));
  unsigned short* Wo = (unsigned short*)(ws + ((size_t)16 << 20));
  unsigned short* P = (unsigned short*)(ws + ((size_t)18 << 20));
  float* nrm = (float*)(ws + ((size_t)50 << 20));

  ln_kernel<<<NTOK, 256, 0, stream>>>(X, Xn);
  cvt_both_kernel<<<5120, 256, 0, stream>>>(W_in, W_out, Wi);
  gemm_p_kernel<<<dim3(32, 32), 256, 0, stream>>>(Xn, Wi, b_in, P, 4096, 4096, 1024);
  transv_kernel<<<dim3(32, 32), 256, 0, stream>>>(P, Vt);
  norms_kernel<<<512, 256, 0, stream>>>(P, nrm);
  attn_kernel<<<dim3(16, 32), 256, 0, stream>>>(P, Vt, nrm, O);
  gemm_out_kernel<<<dim3(8, 32), 256, 0, stream>>>(O, Wo, b_out, X, out, 4096, 1024, 1024);
}